// Round 1
// baseline (949.947 us; speedup 1.0000x reference)
//
#include <hip/hip_runtime.h>
#include <math.h>

#define BT 32768   // B*T
#define Dd 768
#define Hh 1024
#define Bb 32
#define Tt 1024

// ---------------- helpers ----------------
__device__ __forceinline__ float block_reduce_sum_256(float v, float* red4) {
    int tid = threadIdx.x;
    #pragma unroll
    for (int o = 32; o > 0; o >>= 1) v += __shfl_down(v, o);
    __syncthreads();
    if ((tid & 63) == 0) red4[tid >> 6] = v;
    __syncthreads();
    return red4[0] + red4[1] + red4[2] + red4[3];
}

// ---------------- 1. LN stats per token (mu, rstd of emb*attn) ----------------
__global__ __launch_bounds__(256) void ln_stats_kernel(
    const float* __restrict__ emb, const int* __restrict__ attn,
    float* __restrict__ mu_out, float* __restrict__ rstd_out)
{
    int tok  = blockIdx.x * 4 + (threadIdx.x >> 6);
    int lane = threadIdx.x & 63;
    float af = (float)attn[tok];
    const float4* row4 = (const float4*)(emb + (size_t)tok * Dd);
    float4 x[3];
    #pragma unroll
    for (int e = 0; e < 3; ++e) x[e] = row4[lane + 64 * e];
    float s = 0.f;
    #pragma unroll
    for (int e = 0; e < 3; ++e) {
        x[e].x *= af; x[e].y *= af; x[e].z *= af; x[e].w *= af;
        s += x[e].x + x[e].y + x[e].z + x[e].w;
    }
    #pragma unroll
    for (int o = 32; o > 0; o >>= 1) s += __shfl_down(s, o);
    s = __shfl(s, 0);
    float mean = s / 768.0f;
    float q = 0.f;
    #pragma unroll
    for (int e = 0; e < 3; ++e) {
        float d0 = x[e].x - mean, d1 = x[e].y - mean, d2 = x[e].z - mean, d3 = x[e].w - mean;
        q += d0*d0 + d1*d1 + d2*d2 + d3*d3;
    }
    #pragma unroll
    for (int o = 32; o > 0; o >>= 1) q += __shfl_down(q, o);
    if (lane == 0) {
        mu_out[tok]   = mean;
        rstd_out[tok] = 1.0f / sqrtf(q / 768.0f + 1e-5f);
    }
}

// ---------------- 2a. init scores with b2 ----------------
__global__ void init_scores_kernel(const float* __restrict__ b2, float* __restrict__ scores) {
    int i = blockIdx.x * 256 + threadIdx.x;
    scores[i] = b2[0];
}

// ---------------- 2b. fused selector GEMM: scores += sum_h gelu(LN(emb)@w1+b1)*w2 ----
// grid = 512 M-tiles x 8 N-chunks; BM=64, BN=128, BK=32; 256 threads (16x16),
// thread micro-tile 4 rows x 8 cols.
__global__ __launch_bounds__(256) void score_gemm_kernel(
    const float* __restrict__ emb, const int* __restrict__ attn,
    const float* __restrict__ mu, const float* __restrict__ rstd,
    const float* __restrict__ ln_g, const float* __restrict__ ln_b,
    const float* __restrict__ w1, const float* __restrict__ b1,
    const float* __restrict__ w2, float* __restrict__ scores)
{
    __shared__ float As[64][36];          // +pad
    __shared__ float Ws[32][128];
    __shared__ float gfull[768], bfull[768];
    __shared__ float rowmu[64], rowrs[64], rowaf[64];
    __shared__ float red[64][17];

    const int tid  = threadIdx.x;
    const int mblk = blockIdx.x >> 3;
    const int nc   = blockIdx.x & 7;
    const int m0   = mblk * 64;
    const int nb   = nc * 128;
    const int tx   = tid & 15, ty = tid >> 4;

    for (int i = tid; i < 768; i += 256) { gfull[i] = ln_g[i]; bfull[i] = ln_b[i]; }
    if (tid < 64) {
        int t = m0 + tid;
        rowmu[tid] = mu[t]; rowrs[tid] = rstd[t]; rowaf[tid] = (float)attn[t];
    }
    __syncthreads();

    float acc[4][8];
    #pragma unroll
    for (int i = 0; i < 4; ++i)
        #pragma unroll
        for (int j = 0; j < 8; ++j) acc[i][j] = 0.f;

    const int arow = tid >> 2, aseg = tid & 3;
    const float amu = rowmu[arow], ars = rowrs[arow], aaf = rowaf[arow];
    const float* asrc = emb + (size_t)(m0 + arow) * 768 + aseg * 8;

    for (int kk = 0; kk < 24; ++kk) {
        const int kbase = kk * 32;
        // stage A (with LN applied)
        {
            const float* p = asrc + kbase;
            float4 v0 = *(const float4*)p;
            float4 v1 = *(const float4*)(p + 4);
            int d0 = kbase + aseg * 8;
            float vv[8] = {v0.x, v0.y, v0.z, v0.w, v1.x, v1.y, v1.z, v1.w};
            float o[8];
            #pragma unroll
            for (int e = 0; e < 8; ++e)
                o[e] = (vv[e] * aaf - amu) * ars * gfull[d0 + e] + bfull[d0 + e];
            *(float4*)&As[arow][aseg * 8]     = make_float4(o[0], o[1], o[2], o[3]);
            *(float4*)&As[arow][aseg * 8 + 4] = make_float4(o[4], o[5], o[6], o[7]);
        }
        // stage W
        {
            const int wseg = tid & 31, r0 = tid >> 5;
            #pragma unroll
            for (int rr = 0; rr < 4; ++rr) {
                int r = r0 + rr * 8;
                float4 wv = *(const float4*)(w1 + (size_t)(kbase + r) * 1024 + nb + wseg * 4);
                *(float4*)&Ws[r][wseg * 4] = wv;
            }
        }
        __syncthreads();
        // compute 32 k-steps
        #pragma unroll
        for (int k4 = 0; k4 < 8; ++k4) {
            float a_[4][4];
            #pragma unroll
            for (int i = 0; i < 4; ++i) {
                float4 t = *(const float4*)&As[ty * 4 + i][k4 * 4];
                a_[i][0] = t.x; a_[i][1] = t.y; a_[i][2] = t.z; a_[i][3] = t.w;
            }
            #pragma unroll
            for (int kc = 0; kc < 4; ++kc) {
                float4 wA = *(const float4*)&Ws[k4 * 4 + kc][tx * 4];
                float4 wB = *(const float4*)&Ws[k4 * 4 + kc][64 + tx * 4];
                #pragma unroll
                for (int i = 0; i < 4; ++i) {
                    float av = a_[i][kc];
                    acc[i][0] = fmaf(av, wA.x, acc[i][0]);
                    acc[i][1] = fmaf(av, wA.y, acc[i][1]);
                    acc[i][2] = fmaf(av, wA.z, acc[i][2]);
                    acc[i][3] = fmaf(av, wA.w, acc[i][3]);
                    acc[i][4] = fmaf(av, wB.x, acc[i][4]);
                    acc[i][5] = fmaf(av, wB.y, acc[i][5]);
                    acc[i][6] = fmaf(av, wB.z, acc[i][6]);
                    acc[i][7] = fmaf(av, wB.w, acc[i][7]);
                }
            }
        }
        __syncthreads();
    }

    // epilogue: gelu(acc + b1) * w2, reduce over the 8 cols of this thread
    float spart[4];
    #pragma unroll
    for (int i = 0; i < 4; ++i) {
        float s = 0.f;
        #pragma unroll
        for (int j = 0; j < 2; ++j) {
            #pragma unroll
            for (int c = 0; c < 4; ++c) {
                int h = nb + j * 64 + tx * 4 + c;
                float x = acc[i][j * 4 + c] + b1[h];
                float g = 0.5f * x * (1.0f + erff(x * 0.70710678118654752440f));
                s += g * w2[h];
            }
        }
        spart[i] = s;
    }
    #pragma unroll
    for (int i = 0; i < 4; ++i) red[ty * 4 + i][tx] = spart[i];
    __syncthreads();
    if (tid < 64) {
        float s = 0.f;
        #pragma unroll
        for (int x = 0; x < 16; ++x) s += red[tid][x];
        atomicAdd(&scores[m0 + tid], s);
    }
}

// ---------------- 3a. per-batch masked mean/var/T_eff of scores ----------------
__global__ __launch_bounds__(256) void stats_kernel(
    const float* __restrict__ scores, const int* __restrict__ attn,
    float* __restrict__ stat)  // [0..31]=mean [32..63]=rinv [64..95]=teff
{
    __shared__ float red4[4];
    const int b = blockIdx.x, tid = threadIdx.x;
    float sv[4], av[4];
    float sa = 0.f, ss = 0.f;
    #pragma unroll
    for (int e = 0; e < 4; ++e) {
        int i = tid + 256 * e;
        float af = (float)attn[b * 1024 + i];
        float s  = (af != 0.f) ? scores[b * 1024 + i] : 0.f;
        av[e] = af; sv[e] = s;
        sa += af; ss += s;
    }
    float tot_a = block_reduce_sum_256(sa, red4);
    float tot_s = block_reduce_sum_256(ss, red4);
    float denom = fmaxf(tot_a, 1.0f);
    float mean  = tot_s / denom;
    float q = 0.f;
    #pragma unroll
    for (int e = 0; e < 4; ++e) { float d = sv[e] - mean; q += d * d * av[e]; }
    float tot_q = block_reduce_sum_256(q, red4);
    if (tid == 0) {
        stat[b]      = mean;
        stat[32 + b] = 1.0f / sqrtf(tot_q / denom + 1e-6f);
        stat[64 + b] = tot_a;
    }
}

// ---------------- 3b. ranks: r_j = 1 + attn_j * sum_i sigmoid((s_j-s_i)/tau)^2 ----
__global__ __launch_bounds__(256) void rank_kernel(
    const float* __restrict__ scores, const int* __restrict__ attn,
    const float* __restrict__ stat, float* __restrict__ ranks)
{
    __shared__ float sn[1024];
    const int b = blockIdx.x >> 2, q = blockIdx.x & 3;
    const int tid = threadIdx.x;
    const float mean = stat[b], rinv = stat[32 + b];
    #pragma unroll
    for (int e = 0; e < 4; ++e) {
        int i = tid + 256 * e;
        float af = (float)attn[b * 1024 + i];
        float s  = (af != 0.f) ? scores[b * 1024 + i] : 0.f;
        sn[i] = (s - mean) * rinv;
    }
    __syncthreads();
    const int j = q * 256 + tid;
    const float sj = sn[j];
    double sum = 0.0;
    for (int i = 0; i < 1024; ++i) {
        float d   = (sj - sn[i]) * 20.0f;   // 1/tau
        float ee  = expf(-fabsf(d));
        float rcp = 1.0f / (1.0f + ee);
        float sig = (d >= 0.f) ? rcp : ee * rcp;
        sum += (double)(sig * sig);
    }
    float af = (float)attn[b * 1024 + j];
    ranks[b * 1024 + j] = (af == 0.f) ? 1e9f : (float)(1.0 + sum);
}

// ---------------- 3c. pos + gates + g_soft + hard_mask + rho_eff ----------------
__global__ __launch_bounds__(256) void gate_kernel(
    const float* __restrict__ ranks, const int* __restrict__ attn,
    const float* __restrict__ stat, float* __restrict__ w_rho,
    float* __restrict__ keff, float* __restrict__ out)
{
    __shared__ float rk[1024];
    __shared__ float red4[4];
    const int b = blockIdx.x, tid = threadIdx.x;
    const float teff = stat[64 + b];
    #pragma unroll
    for (int e = 0; e < 4; ++e) rk[tid + 256 * e] = ranks[b * 1024 + tid + 256 * e];
    __syncthreads();
    float rj[4], afj[4];
    int pos[4];
    #pragma unroll
    for (int e = 0; e < 4; ++e) {
        int j = tid + 256 * e;
        rj[e]  = rk[j];
        afj[e] = (float)attn[b * 1024 + j];
        int c = 0;
        for (int i = 0; i < 1024; ++i) {
            float ri = rk[i];
            c += (ri < rj[e]) ? 1 : ((ri == rj[e] && i < j) ? 1 : 0);
        }
        pos[e] = c;
    }
    const float rhos[3] = {0.1f, 0.25f, 0.5f};
    #pragma unroll 1
    for (int r = 0; r < 3; ++r) {
        float k = fmaxf(rintf(rhos[r] * teff), 1.0f);
        float gate[4]; float lsum = 0.f;
        #pragma unroll
        for (int e = 0; e < 4; ++e) {
            float d   = (k - rj[e]) / 0.2f;
            float ee  = expf(-fabsf(d));
            float rcp = 1.0f / (1.0f + ee);
            float sig = (d >= 0.f) ? rcp : ee * rcp;
            gate[e] = sig * afj[e];
            lsum += gate[e];
        }
        float gsum = block_reduce_sum_256(lsum, red4);
        float cl   = fmaxf(gsum, 1e-8f);
        float ls2  = 0.f;
        #pragma unroll
        for (int e = 0; e < 4; ++e) {
            int j = tid + 256 * e;
            float gs = gate[e] / cl * k;
            ls2 += gs;
            w_rho[r * BT + b * 1024 + j]     = gs;
            out[BT + r * BT + b * 1024 + j]  = ((float)pos[e] < k) ? 1.0f : 0.0f;
            if (r == 2) out[b * 1024 + j] = gs;
        }
        float ks = block_reduce_sum_256(ls2, red4);
        if (tid == 0) {
            keff[r * Bb + b] = ks;
            out[131076 + r * Bb + b] = ks / fmaxf(teff, 1.0f);
        }
    }
}

// ---------------- 4. pooling: 4 weighted sums over emb_table[ids] ----------------
__global__ __launch_bounds__(256) void pool_kernel(
    const int* __restrict__ ids, const int* __restrict__ attn,
    const float* __restrict__ emb_table, const float* __restrict__ w_rho,
    float* __restrict__ pacc)   // [4][32][768], slot 3 = full (attn weights)
{
    const int b = blockIdx.x >> 3, chunk = blockIdx.x & 7;
    const int tid = threadIdx.x;
    float accF[3] = {0,0,0}, acc0[3] = {0,0,0}, acc1[3] = {0,0,0}, acc2[3] = {0,0,0};
    const int t0 = chunk * 128;
    for (int t = t0; t < t0 + 128; ++t) {
        int gi = b * 1024 + t;
        if (attn[gi] == 0) continue;     // all four weights are zero
        float w0 = w_rho[gi], wa = w_rho[BT + gi], wb = w_rho[2 * BT + gi];
        const float* row = emb_table + (size_t)ids[gi] * 768;
        #pragma unroll
        for (int e = 0; e < 3; ++e) {
            float v = row[tid + 256 * e];
            accF[e] += v;
            acc0[e] = fmaf(w0, v, acc0[e]);
            acc1[e] = fmaf(wa, v, acc1[e]);
            acc2[e] = fmaf(wb, v, acc2[e]);
        }
    }
    #pragma unroll
    for (int e = 0; e < 3; ++e) {
        int d = tid + 256 * e;
        atomicAdd(&pacc[(0 * Bb + b) * 768 + d], acc0[e]);
        atomicAdd(&pacc[(1 * Bb + b) * 768 + d], acc1[e]);
        atomicAdd(&pacc[(2 * Bb + b) * 768 + d], acc2[e]);
        atomicAdd(&pacc[(3 * Bb + b) * 768 + d], accF[e]);
    }
}

// ---------------- 5. losses + recon_avg ----------------
__global__ __launch_bounds__(256) void final_kernel(
    const float* __restrict__ pacc, const float* __restrict__ keff,
    const float* __restrict__ stat, float* __restrict__ out)
{
    __shared__ float red4[4];
    const int tid = threadIdx.x;
    float lsum[3];
    #pragma unroll 1
    for (int r = 0; r < 3; ++r) {
        float local = 0.f;
        for (int idx = tid; idx < Bb * 768; idx += 256) {
            int b = idx / 768;
            int d = idx - b * 768;
            float fullv = pacc[(3 * Bb + b) * 768 + d] / fmaxf(stat[64 + b], 1e-9f);
            float predv = pacc[(r * Bb + b) * 768 + d] / fmaxf(keff[r * Bb + b], 1e-9f);
            float df = predv - fullv;
            local += df * df;
        }
        float tot = block_reduce_sum_256(local, red4);
        lsum[r] = tot / 24576.0f;
    }
    if (tid == 0) {
        out[131073] = lsum[0];
        out[131074] = lsum[1];
        out[131075] = lsum[2];
        out[131072] = (lsum[0] + lsum[1] + lsum[2]) / 3.0f;
    }
}

// ---------------- launch ----------------
extern "C" void kernel_launch(void* const* d_in, const int* in_sizes, int n_in,
                              void* d_out, int out_size, void* d_ws, size_t ws_size,
                              hipStream_t stream) {
    const int*   ids       = (const int*)d_in[0];
    const float* emb       = (const float*)d_in[1];
    const int*   attn      = (const int*)d_in[2];
    const float* ln_g      = (const float*)d_in[3];
    const float* ln_b      = (const float*)d_in[4];
    const float* w1        = (const float*)d_in[5];
    const float* b1        = (const float*)d_in[6];
    const float* w2        = (const float*)d_in[7];
    const float* b2        = (const float*)d_in[8];
    const float* emb_table = (const float*)d_in[9];
    float* out = (float*)d_out;
    float* ws  = (float*)d_ws;

    float* mu     = ws;               // 32768
    float* rstd   = ws + 32768;       // 32768
    float* scores = ws + 65536;       // 32768
    float* ranks  = ws + 98304;       // 32768
    float* w_rho  = ws + 131072;      // 3*32768
    float* stat   = ws + 229376;      // 96
    float* keff   = ws + 229472;      // 96
    float* pacc   = ws + 229568;      // 4*32*768 = 98304

    hipMemsetAsync(pacc, 0, 98304 * sizeof(float), stream);
    ln_stats_kernel<<<8192, 256, 0, stream>>>(emb, attn, mu, rstd);
    init_scores_kernel<<<128, 256, 0, stream>>>(b2, scores);
    score_gemm_kernel<<<4096, 256, 0, stream>>>(emb, attn, mu, rstd, ln_g, ln_b,
                                                w1, b1, w2, scores);
    stats_kernel<<<32, 256, 0, stream>>>(scores, attn, stat);
    rank_kernel<<<128, 256, 0, stream>>>(scores, attn, stat, ranks);
    gate_kernel<<<32, 256, 0, stream>>>(ranks, attn, stat, w_rho, keff, out);
    pool_kernel<<<256, 256, 0, stream>>>(ids, attn, emb_table, w_rho, pacc);
    final_kernel<<<1, 256, 0, stream>>>(pacc, keff, stat, out);
}

// Round 2
// 611.831 us; speedup vs baseline: 1.5526x; 1.5526x over previous
//
#include <hip/hip_runtime.h>
#include <math.h>

#define BT 32768   // B*T
#define Dd 768
#define Hh 1024
#define Bb 32
#define Tt 1024
#define HALF_M 16384

typedef __bf16 bf16x8 __attribute__((ext_vector_type(8)));
typedef float f32x4 __attribute__((ext_vector_type(4)));

#define GL2LDS16(gp, lp) __builtin_amdgcn_global_load_lds( \
    (const __attribute__((address_space(1))) void*)(gp),   \
    (__attribute__((address_space(3))) void*)(lp), 16, 0, 0)

// ---------------- helpers ----------------
__device__ __forceinline__ float block_reduce_sum_256(float v, float* red4) {
    int tid = threadIdx.x;
    #pragma unroll
    for (int o = 32; o > 0; o >>= 1) v += __shfl_down(v, o);
    __syncthreads();
    if ((tid & 63) == 0) red4[tid >> 6] = v;
    __syncthreads();
    return red4[0] + red4[1] + red4[2] + red4[3];
}

__device__ __forceinline__ void bf16split(float x, short& h, short& l) {
    unsigned u = __float_as_uint(x);
    unsigned r = (u + 0x7FFFu + ((u >> 16) & 1u)) >> 16;     // RNE to bf16
    h = (short)r;
    float fh = __uint_as_float(r << 16);
    float lof = x - fh;
    unsigned u2 = __float_as_uint(lof);
    unsigned r2 = (u2 + 0x7FFFu + ((u2 >> 16) & 1u)) >> 16;
    l = (short)r2;
}

__device__ __forceinline__ int pack2(short a, short b) {
    return (int)(unsigned short)a | ((int)(unsigned short)b << 16);
}

// ---------------- 1. prep A: LN + bf16 hi/lo split (one wave per token) -------
__global__ __launch_bounds__(256) void prep_a_kernel(
    const float* __restrict__ emb, const int* __restrict__ attn,
    const float* __restrict__ ln_g, const float* __restrict__ ln_b,
    short* __restrict__ a_hi, short* __restrict__ a_lo)
{
    int tok  = blockIdx.x * 4 + (threadIdx.x >> 6);
    int lane = threadIdx.x & 63;
    float af = (float)attn[tok];
    const float4* row4 = (const float4*)(emb + (size_t)tok * Dd);
    float4 x[3];
    #pragma unroll
    for (int e = 0; e < 3; ++e) x[e] = row4[lane + 64 * e];
    float s = 0.f;
    #pragma unroll
    for (int e = 0; e < 3; ++e) {
        x[e].x *= af; x[e].y *= af; x[e].z *= af; x[e].w *= af;
        s += x[e].x + x[e].y + x[e].z + x[e].w;
    }
    #pragma unroll
    for (int o = 32; o > 0; o >>= 1) s += __shfl_down(s, o);
    s = __shfl(s, 0);
    float mean = s / 768.0f;
    float q = 0.f;
    #pragma unroll
    for (int e = 0; e < 3; ++e) {
        float d0 = x[e].x - mean, d1 = x[e].y - mean, d2 = x[e].z - mean, d3 = x[e].w - mean;
        q += d0*d0 + d1*d1 + d2*d2 + d3*d3;
    }
    #pragma unroll
    for (int o = 32; o > 0; o >>= 1) q += __shfl_down(q, o);
    q = __shfl(q, 0);
    float rstd = 1.0f / sqrtf(q / 768.0f + 1e-5f);

    #pragma unroll
    for (int e = 0; e < 3; ++e) {
        int idx = lane * 4 + e * 256;
        float4 g4 = *(const float4*)(ln_g + idx);
        float4 b4 = *(const float4*)(ln_b + idx);
        float o0 = (x[e].x - mean) * rstd * g4.x + b4.x;
        float o1 = (x[e].y - mean) * rstd * g4.y + b4.y;
        float o2 = (x[e].z - mean) * rstd * g4.z + b4.z;
        float o3 = (x[e].w - mean) * rstd * g4.w + b4.w;
        short h0,h1,h2,h3,l0,l1,l2,l3;
        bf16split(o0,h0,l0); bf16split(o1,h1,l1);
        bf16split(o2,h2,l2); bf16split(o3,h3,l3);
        *(int2*)(a_hi + (size_t)tok * 768 + idx) = make_int2(pack2(h0,h1), pack2(h2,h3));
        *(int2*)(a_lo + (size_t)tok * 768 + idx) = make_int2(pack2(l0,l1), pack2(l2,l3));
    }
}

// ---------------- 2. prep W1^T: transpose + bf16 hi/lo split -------------------
__global__ __launch_bounds__(256) void prep_w1t_kernel(
    const float* __restrict__ w1, short* __restrict__ w1t_hi, short* __restrict__ w1t_lo)
{
    __shared__ float tile[32][65];
    const int kb  = blockIdx.x % 24;         // k block of 32
    const int nb0 = (blockIdx.x / 24) * 64;  // n block of 64
    const int tid = threadIdx.x;
    const int r0 = tid >> 6, c = tid & 63;
    #pragma unroll
    for (int rr = 0; rr < 8; ++rr) {
        int k = kb * 32 + r0 + rr * 4;
        tile[r0 + rr * 4][c] = w1[(size_t)k * 1024 + nb0 + c];
    }
    __syncthreads();
    const int n = tid >> 2, kc = (tid & 3) * 8;
    short h[8], lo[8];
    #pragma unroll
    for (int e = 0; e < 8; ++e) bf16split(tile[kc + e][n], h[e], lo[e]);
    size_t off = (size_t)(nb0 + n) * 768 + kb * 32 + kc;
    *(int4*)(w1t_hi + off) = make_int4(pack2(h[0],h[1]), pack2(h[2],h[3]),
                                       pack2(h[4],h[5]), pack2(h[6],h[7]));
    *(int4*)(w1t_lo + off) = make_int4(pack2(lo[0],lo[1]), pack2(lo[2],lo[3]),
                                       pack2(lo[4],lo[5]), pack2(lo[6],lo[7]));
}

// ---------------- 3a. init scores with b2 ----------------
__global__ void init_scores_kernel(const float* __restrict__ b2, float* __restrict__ scores) {
    int i = blockIdx.x * 256 + threadIdx.x;
    scores[i] = b2[0];
}

// ---------------- 3b. MFMA GEMM (bf16 hi/lo x3) + gelu*w2 epilogue ------------
// grid = 128 mtiles x 8 nchunks (bid = nc*128 + mt so same-mt blocks share XCD);
// block 256 thr = 4 waves (2x2), per-wave 64x64 output, BK=32, dbuf LDS.
__global__ __launch_bounds__(256) void score_gemm_mfma(
    const __bf16* __restrict__ a_hi, const __bf16* __restrict__ a_lo,
    const __bf16* __restrict__ w1t_hi, const __bf16* __restrict__ w1t_lo,
    const float* __restrict__ b1, const float* __restrict__ w2,
    float* __restrict__ scores)
{
    __shared__ __bf16 sAh[2][8][512];
    __shared__ __bf16 sAl[2][8][512];
    __shared__ __bf16 sBh[2][8][512];
    __shared__ __bf16 sBl[2][8][512];

    const int tid = threadIdx.x;
    const int l   = tid & 63;
    const int w   = tid >> 6;
    const int mt  = blockIdx.x & 127;
    const int nc  = blockIdx.x >> 7;
    const int m0  = mt * 128;
    const int nb  = nc * 128;

    const int rsel = l & 15;
    const int ksel = (l >> 4) * 8;
    const int s0   = 2 * w;

    const size_t aA0 = (size_t)(m0 + s0 * 16 + rsel) * 768 + ksel;
    const size_t aA1 = aA0 + 16 * 768;
    const size_t aB0 = (size_t)(nb + s0 * 16 + rsel) * 768 + ksel;
    const size_t aB1 = aB0 + 16 * 768;

    f32x4 acc[4][4];
    #pragma unroll
    for (int i = 0; i < 4; ++i)
        #pragma unroll
        for (int j = 0; j < 4; ++j) acc[i][j] = (f32x4){0.f, 0.f, 0.f, 0.f};

    auto stage = [&](int buf, int k0) {
        GL2LDS16(a_hi   + aA0 + k0, &sAh[buf][s0][0]);
        GL2LDS16(a_hi   + aA1 + k0, &sAh[buf][s0 + 1][0]);
        GL2LDS16(a_lo   + aA0 + k0, &sAl[buf][s0][0]);
        GL2LDS16(a_lo   + aA1 + k0, &sAl[buf][s0 + 1][0]);
        GL2LDS16(w1t_hi + aB0 + k0, &sBh[buf][s0][0]);
        GL2LDS16(w1t_hi + aB1 + k0, &sBh[buf][s0 + 1][0]);
        GL2LDS16(w1t_lo + aB0 + k0, &sBl[buf][s0][0]);
        GL2LDS16(w1t_lo + aB1 + k0, &sBl[buf][s0 + 1][0]);
    };

    stage(0, 0);
    const int wr = w >> 1, wc = w & 1;

    for (int kt = 0; kt < 24; ++kt) {
        const int cur = kt & 1;
        __syncthreads();                       // stage(cur) complete; prior reads done
        if (kt < 23) stage(cur ^ 1, (kt + 1) * 32);

        bf16x8 ah[4], al[4], bh[4], bl[4];
        #pragma unroll
        for (int mi = 0; mi < 4; ++mi) {
            ah[mi] = *(const bf16x8*)&sAh[cur][wr * 4 + mi][l * 8];
            al[mi] = *(const bf16x8*)&sAl[cur][wr * 4 + mi][l * 8];
        }
        #pragma unroll
        for (int ni = 0; ni < 4; ++ni) {
            bh[ni] = *(const bf16x8*)&sBh[cur][wc * 4 + ni][l * 8];
            bl[ni] = *(const bf16x8*)&sBl[cur][wc * 4 + ni][l * 8];
        }
        #pragma unroll
        for (int mi = 0; mi < 4; ++mi)
            #pragma unroll
            for (int ni = 0; ni < 4; ++ni) {
                acc[mi][ni] = __builtin_amdgcn_mfma_f32_16x16x32_bf16(ah[mi], bh[ni], acc[mi][ni], 0, 0, 0);
                acc[mi][ni] = __builtin_amdgcn_mfma_f32_16x16x32_bf16(al[mi], bh[ni], acc[mi][ni], 0, 0, 0);
                acc[mi][ni] = __builtin_amdgcn_mfma_f32_16x16x32_bf16(ah[mi], bl[ni], acc[mi][ni], 0, 0, 0);
            }
    }

    // epilogue: scores[row] += sum_col gelu(acc + b1[col]) * w2[col]
    // C/D frag: col = lane&15, row = (lane>>4)*4 + j
    const int colbase = nb + wc * 64 + (l & 15);
    const int rowg    = (l >> 4) * 4;
    #pragma unroll
    for (int mi = 0; mi < 4; ++mi) {
        float v[4] = {0.f, 0.f, 0.f, 0.f};
        #pragma unroll
        for (int ni = 0; ni < 4; ++ni) {
            int col = colbase + ni * 16;
            float b1v = b1[col], w2v = w2[col];
            #pragma unroll
            for (int j = 0; j < 4; ++j) {
                float x = acc[mi][ni][j] + b1v;
                float g = 0.5f * x * (1.0f + erff(x * 0.70710678118654752440f));
                v[j] = fmaf(g, w2v, v[j]);
            }
        }
        #pragma unroll
        for (int j = 0; j < 4; ++j) {
            v[j] += __shfl_xor(v[j], 1);
            v[j] += __shfl_xor(v[j], 2);
            v[j] += __shfl_xor(v[j], 4);
            v[j] += __shfl_xor(v[j], 8);
        }
        if ((l & 15) == 0) {
            int row = m0 + wr * 64 + mi * 16 + rowg;
            #pragma unroll
            for (int j = 0; j < 4; ++j) atomicAdd(&scores[row + j], v[j]);
        }
    }
}

// ---------------- 4a. per-batch masked mean/var/T_eff of scores ----------------
__global__ __launch_bounds__(256) void stats_kernel(
    const float* __restrict__ scores, const int* __restrict__ attn,
    float* __restrict__ stat)  // [0..31]=mean [32..63]=rinv [64..95]=teff
{
    __shared__ float red4[4];
    const int b = blockIdx.x, tid = threadIdx.x;
    float sv[4], av[4];
    float sa = 0.f, ss = 0.f;
    #pragma unroll
    for (int e = 0; e < 4; ++e) {
        int i = tid + 256 * e;
        float af = (float)attn[b * 1024 + i];
        float s  = (af != 0.f) ? scores[b * 1024 + i] : 0.f;
        av[e] = af; sv[e] = s;
        sa += af; ss += s;
    }
    float tot_a = block_reduce_sum_256(sa, red4);
    float tot_s = block_reduce_sum_256(ss, red4);
    float denom = fmaxf(tot_a, 1.0f);
    float mean  = tot_s / denom;
    float q = 0.f;
    #pragma unroll
    for (int e = 0; e < 4; ++e) { float d = sv[e] - mean; q += d * d * av[e]; }
    float tot_q = block_reduce_sum_256(q, red4);
    if (tid == 0) {
        stat[b]      = mean;
        stat[32 + b] = 1.0f / sqrtf(tot_q / denom + 1e-6f);
        stat[64 + b] = tot_a;
    }
}

// ---------------- 4b. ranks ----------------
__global__ __launch_bounds__(256) void rank_kernel(
    const float* __restrict__ scores, const int* __restrict__ attn,
    const float* __restrict__ stat, float* __restrict__ ranks)
{
    __shared__ float sn[1024];
    const int b = blockIdx.x >> 2, q = blockIdx.x & 3;
    const int tid = threadIdx.x;
    const float mean = stat[b], rinv = stat[32 + b];
    #pragma unroll
    for (int e = 0; e < 4; ++e) {
        int i = tid + 256 * e;
        float af = (float)attn[b * 1024 + i];
        float s  = (af != 0.f) ? scores[b * 1024 + i] : 0.f;
        sn[i] = (s - mean) * rinv;
    }
    __syncthreads();
    const int j = q * 256 + tid;
    const float sj = sn[j];
    double sum = 0.0;
    for (int i = 0; i < 1024; ++i) {
        float d   = (sj - sn[i]) * 20.0f;   // 1/tau
        float ee  = expf(-fabsf(d));
        float rcp = 1.0f / (1.0f + ee);
        float sig = (d >= 0.f) ? rcp : ee * rcp;
        sum += (double)(sig * sig);
    }
    float af = (float)attn[b * 1024 + j];
    ranks[b * 1024 + j] = (af == 0.f) ? 1e9f : (float)(1.0 + sum);
}

// ---------------- 4c. pos + gates + g_soft + hard_mask + rho_eff ----------------
__global__ __launch_bounds__(256) void gate_kernel(
    const float* __restrict__ ranks, const int* __restrict__ attn,
    const float* __restrict__ stat, float* __restrict__ w_rho,
    float* __restrict__ keff, float* __restrict__ out)
{
    __shared__ float rk[1024];
    __shared__ float red4[4];
    const int b = blockIdx.x, tid = threadIdx.x;
    const float teff = stat[64 + b];
    #pragma unroll
    for (int e = 0; e < 4; ++e) rk[tid + 256 * e] = ranks[b * 1024 + tid + 256 * e];
    __syncthreads();
    float rj[4], afj[4];
    int pos[4];
    #pragma unroll
    for (int e = 0; e < 4; ++e) {
        int j = tid + 256 * e;
        rj[e]  = rk[j];
        afj[e] = (float)attn[b * 1024 + j];
        int c = 0;
        for (int i = 0; i < 1024; ++i) {
            float ri = rk[i];
            c += (ri < rj[e]) ? 1 : ((ri == rj[e] && i < j) ? 1 : 0);
        }
        pos[e] = c;
    }
    const float rhos[3] = {0.1f, 0.25f, 0.5f};
    #pragma unroll 1
    for (int r = 0; r < 3; ++r) {
        float k = fmaxf(rintf(rhos[r] * teff), 1.0f);
        float gate[4]; float lsum = 0.f;
        #pragma unroll
        for (int e = 0; e < 4; ++e) {
            float d   = (k - rj[e]) / 0.2f;
            float ee  = expf(-fabsf(d));
            float rcp = 1.0f / (1.0f + ee);
            float sig = (d >= 0.f) ? rcp : ee * rcp;
            gate[e] = sig * afj[e];
            lsum += gate[e];
        }
        float gsum = block_reduce_sum_256(lsum, red4);
        float cl   = fmaxf(gsum, 1e-8f);
        float ls2  = 0.f;
        #pragma unroll
        for (int e = 0; e < 4; ++e) {
            int j = tid + 256 * e;
            float gs = gate[e] / cl * k;
            ls2 += gs;
            w_rho[r * BT + b * 1024 + j]     = gs;
            out[BT + r * BT + b * 1024 + j]  = ((float)pos[e] < k) ? 1.0f : 0.0f;
            if (r == 2) out[b * 1024 + j] = gs;
        }
        float ks = block_reduce_sum_256(ls2, red4);
        if (tid == 0) {
            keff[r * Bb + b] = ks;
            out[131076 + r * Bb + b] = ks / fmaxf(teff, 1.0f);
        }
    }
}

// ---------------- 5. pooling ----------------
__global__ __launch_bounds__(256) void pool_kernel(
    const int* __restrict__ ids, const int* __restrict__ attn,
    const float* __restrict__ emb_table, const float* __restrict__ w_rho,
    float* __restrict__ pacc)   // [4][32][768], slot 3 = full (attn weights)
{
    const int b = blockIdx.x >> 3, chunk = blockIdx.x & 7;
    const int tid = threadIdx.x;
    float accF[3] = {0,0,0}, acc0[3] = {0,0,0}, acc1[3] = {0,0,0}, acc2[3] = {0,0,0};
    const int t0 = chunk * 128;
    for (int t = t0; t < t0 + 128; ++t) {
        int gi = b * 1024 + t;
        if (attn[gi] == 0) continue;
        float w0 = w_rho[gi], wa = w_rho[BT + gi], wb = w_rho[2 * BT + gi];
        const float* row = emb_table + (size_t)ids[gi] * 768;
        #pragma unroll
        for (int e = 0; e < 3; ++e) {
            float v = row[tid + 256 * e];
            accF[e] += v;
            acc0[e] = fmaf(w0, v, acc0[e]);
            acc1[e] = fmaf(wa, v, acc1[e]);
            acc2[e] = fmaf(wb, v, acc2[e]);
        }
    }
    #pragma unroll
    for (int e = 0; e < 3; ++e) {
        int d = tid + 256 * e;
        atomicAdd(&pacc[(0 * Bb + b) * 768 + d], acc0[e]);
        atomicAdd(&pacc[(1 * Bb + b) * 768 + d], acc1[e]);
        atomicAdd(&pacc[(2 * Bb + b) * 768 + d], acc2[e]);
        atomicAdd(&pacc[(3 * Bb + b) * 768 + d], accF[e]);
    }
}

// ---------------- 6. losses + recon_avg ----------------
__global__ __launch_bounds__(256) void final_kernel(
    const float* __restrict__ pacc, const float* __restrict__ keff,
    const float* __restrict__ stat, float* __restrict__ out)
{
    __shared__ float red4[4];
    const int tid = threadIdx.x;
    float lsum[3];
    #pragma unroll 1
    for (int r = 0; r < 3; ++r) {
        float local = 0.f;
        for (int idx = tid; idx < Bb * 768; idx += 256) {
            int b = idx / 768;
            int d = idx - b * 768;
            float fullv = pacc[(3 * Bb + b) * 768 + d] / fmaxf(stat[64 + b], 1e-9f);
            float predv = pacc[(r * Bb + b) * 768 + d] / fmaxf(keff[r * Bb + b], 1e-9f);
            float df = predv - fullv;
            local += df * df;
        }
        float tot = block_reduce_sum_256(local, red4);
        lsum[r] = tot / 24576.0f;
    }
    if (tid == 0) {
        out[131073] = lsum[0];
        out[131074] = lsum[1];
        out[131075] = lsum[2];
        out[131072] = (lsum[0] + lsum[1] + lsum[2]) / 3.0f;
    }
}

// ---------------- launch ----------------
extern "C" void kernel_launch(void* const* d_in, const int* in_sizes, int n_in,
                              void* d_out, int out_size, void* d_ws, size_t ws_size,
                              hipStream_t stream) {
    const int*   ids       = (const int*)d_in[0];
    const float* emb       = (const float*)d_in[1];
    const int*   attn      = (const int*)d_in[2];
    const float* ln_g      = (const float*)d_in[3];
    const float* ln_b      = (const float*)d_in[4];
    const float* w1        = (const float*)d_in[5];
    const float* b1        = (const float*)d_in[6];
    const float* w2        = (const float*)d_in[7];
    const float* b2        = (const float*)d_in[8];
    const float* emb_table = (const float*)d_in[9];
    float* out = (float*)d_out;
    float* ws  = (float*)d_ws;

    float* scores = ws;                    // 32768
    float* ranks  = ws + 32768;            // 32768
    float* w_rho  = ws + 65536;            // 3*32768
    float* stat   = ws + 163840;           // 96
    float* keff   = ws + 163936;           // 96
    float* pacc   = ws + 164032;           // 98304 (ends 262336)
    short* a_hi   = (short*)(ws + 262400);         // 16384*768 shorts
    short* a_lo   = a_hi + (size_t)HALF_M * 768;   // 16384*768 shorts
    short* w1t_hi = a_lo + (size_t)HALF_M * 768;   // 1024*768 shorts
    short* w1t_lo = w1t_hi + 1024 * 768;           // 1024*768 shorts

    hipMemsetAsync(pacc, 0, 98304 * sizeof(float), stream);
    init_scores_kernel<<<128, 256, 0, stream>>>(b2, scores);
    prep_w1t_kernel<<<384, 256, 0, stream>>>(w1, w1t_hi, w1t_lo);

    for (int h = 0; h < 2; ++h) {
        prep_a_kernel<<<4096, 256, 0, stream>>>(
            emb + (size_t)h * HALF_M * 768, attn + h * HALF_M, ln_g, ln_b, a_hi, a_lo);
        score_gemm_mfma<<<1024, 256, 0, stream>>>(
            (const __bf16*)a_hi, (const __bf16*)a_lo,
            (const __bf16*)w1t_hi, (const __bf16*)w1t_lo,
            b1, w2, scores + (size_t)h * HALF_M);
    }

    stats_kernel<<<32, 256, 0, stream>>>(scores, attn, stat);
    rank_kernel<<<128, 256, 0, stream>>>(scores, attn, stat, ranks);
    gate_kernel<<<32, 256, 0, stream>>>(ranks, attn, stat, w_rho, keff, out);
    pool_kernel<<<256, 256, 0, stream>>>(ids, attn, emb_table, w_rho, pacc);
    final_kernel<<<1, 256, 0, stream>>>(pacc, keff, stat, out);
}

// Round 3
// 546.722 us; speedup vs baseline: 1.7375x; 1.1191x over previous
//
#include <hip/hip_runtime.h>
#include <math.h>

#define BT 32768   // B*T
#define Dd 768
#define Hh 1024
#define Bb 32
#define Tt 1024
#define HALF_M 16384

typedef __bf16 bf16x8 __attribute__((ext_vector_type(8)));
typedef float f32x4 __attribute__((ext_vector_type(4)));

#define GL2LDS16(gp, lp) __builtin_amdgcn_global_load_lds( \
    (const __attribute__((address_space(1))) void*)(gp),   \
    (__attribute__((address_space(3))) void*)(lp), 16, 0, 0)

// ---------------- helpers ----------------
__device__ __forceinline__ float block_reduce_sum_256(float v, float* red4) {
    int tid = threadIdx.x;
    #pragma unroll
    for (int o = 32; o > 0; o >>= 1) v += __shfl_down(v, o);
    __syncthreads();
    if ((tid & 63) == 0) red4[tid >> 6] = v;
    __syncthreads();
    return red4[0] + red4[1] + red4[2] + red4[3];
}

__device__ __forceinline__ void bf16split(float x, short& h, short& l) {
    unsigned u = __float_as_uint(x);
    unsigned r = (u + 0x7FFFu + ((u >> 16) & 1u)) >> 16;     // RNE to bf16
    h = (short)r;
    float fh = __uint_as_float(r << 16);
    float lof = x - fh;
    unsigned u2 = __float_as_uint(lof);
    unsigned r2 = (u2 + 0x7FFFu + ((u2 >> 16) & 1u)) >> 16;
    l = (short)r2;
}

__device__ __forceinline__ int pack2(short a, short b) {
    return (int)(unsigned short)a | ((int)(unsigned short)b << 16);
}

// ---------------- 1. prep A: LN + bf16 hi/lo split (one wave per token) -------
__global__ __launch_bounds__(256) void prep_a_kernel(
    const float* __restrict__ emb, const int* __restrict__ attn,
    const float* __restrict__ ln_g, const float* __restrict__ ln_b,
    short* __restrict__ a_hi, short* __restrict__ a_lo)
{
    int tok  = blockIdx.x * 4 + (threadIdx.x >> 6);
    int lane = threadIdx.x & 63;
    float af = (float)attn[tok];
    const float4* row4 = (const float4*)(emb + (size_t)tok * Dd);
    float4 x[3];
    #pragma unroll
    for (int e = 0; e < 3; ++e) x[e] = row4[lane + 64 * e];
    float s = 0.f;
    #pragma unroll
    for (int e = 0; e < 3; ++e) {
        x[e].x *= af; x[e].y *= af; x[e].z *= af; x[e].w *= af;
        s += x[e].x + x[e].y + x[e].z + x[e].w;
    }
    #pragma unroll
    for (int o = 32; o > 0; o >>= 1) s += __shfl_down(s, o);
    s = __shfl(s, 0);
    float mean = s / 768.0f;
    float q = 0.f;
    #pragma unroll
    for (int e = 0; e < 3; ++e) {
        float d0 = x[e].x - mean, d1 = x[e].y - mean, d2 = x[e].z - mean, d3 = x[e].w - mean;
        q += d0*d0 + d1*d1 + d2*d2 + d3*d3;
    }
    #pragma unroll
    for (int o = 32; o > 0; o >>= 1) q += __shfl_down(q, o);
    q = __shfl(q, 0);
    float rstd = 1.0f / sqrtf(q / 768.0f + 1e-5f);

    #pragma unroll
    for (int e = 0; e < 3; ++e) {
        int idx = lane * 4 + e * 256;
        float4 g4 = *(const float4*)(ln_g + idx);
        float4 b4 = *(const float4*)(ln_b + idx);
        float o0 = (x[e].x - mean) * rstd * g4.x + b4.x;
        float o1 = (x[e].y - mean) * rstd * g4.y + b4.y;
        float o2 = (x[e].z - mean) * rstd * g4.z + b4.z;
        float o3 = (x[e].w - mean) * rstd * g4.w + b4.w;
        short h0,h1,h2,h3,l0,l1,l2,l3;
        bf16split(o0,h0,l0); bf16split(o1,h1,l1);
        bf16split(o2,h2,l2); bf16split(o3,h3,l3);
        *(int2*)(a_hi + (size_t)tok * 768 + idx) = make_int2(pack2(h0,h1), pack2(h2,h3));
        *(int2*)(a_lo + (size_t)tok * 768 + idx) = make_int2(pack2(l0,l1), pack2(l2,l3));
    }
}

// ---------------- 2. prep W1^T: transpose + bf16 hi/lo split -------------------
__global__ __launch_bounds__(256) void prep_w1t_kernel(
    const float* __restrict__ w1, short* __restrict__ w1t_hi, short* __restrict__ w1t_lo)
{
    __shared__ float tile[32][65];
    const int kb  = blockIdx.x % 24;         // k block of 32
    const int nb0 = (blockIdx.x / 24) * 64;  // n block of 64
    const int tid = threadIdx.x;
    const int r0 = tid >> 6, c = tid & 63;
    #pragma unroll
    for (int rr = 0; rr < 8; ++rr) {
        int k = kb * 32 + r0 + rr * 4;
        tile[r0 + rr * 4][c] = w1[(size_t)k * 1024 + nb0 + c];
    }
    __syncthreads();
    const int n = tid >> 2, kc = (tid & 3) * 8;
    short h[8], lo[8];
    #pragma unroll
    for (int e = 0; e < 8; ++e) bf16split(tile[kc + e][n], h[e], lo[e]);
    size_t off = (size_t)(nb0 + n) * 768 + kb * 32 + kc;
    *(int4*)(w1t_hi + off) = make_int4(pack2(h[0],h[1]), pack2(h[2],h[3]),
                                       pack2(h[4],h[5]), pack2(h[6],h[7]));
    *(int4*)(w1t_lo + off) = make_int4(pack2(lo[0],lo[1]), pack2(lo[2],lo[3]),
                                       pack2(lo[4],lo[5]), pack2(lo[6],lo[7]));
}

// ---------------- 3a. init scores with b2 ----------------
__global__ void init_scores_kernel(const float* __restrict__ b2, float* __restrict__ scores) {
    int i = blockIdx.x * 256 + threadIdx.x;
    scores[i] = b2[0];
}

// ---------------- 3b. MFMA GEMM: A hi/lo in LDS, B frags direct from L2 -------
// grid = 128 mtiles x 8 nchunks (bid = nc*128 + mt: the 8 nc-copies of an
// mtile share bid%8 -> same XCD -> A-tile L2 reuse). 4 waves (2x2), 64x64 each.
__global__ __launch_bounds__(256) void score_gemm_mfma(
    const __bf16* __restrict__ a_hi, const __bf16* __restrict__ a_lo,
    const __bf16* __restrict__ w1t_hi, const __bf16* __restrict__ w1t_lo,
    const float* __restrict__ b1, const float* __restrict__ w2,
    float* __restrict__ scores)
{
    __shared__ __align__(16) __bf16 sAh[2][8][512];
    __shared__ __align__(16) __bf16 sAl[2][8][512];

    const int tid = threadIdx.x;
    const int l   = tid & 63;
    const int w   = tid >> 6;
    const int mt  = blockIdx.x & 127;
    const int nc  = blockIdx.x >> 7;
    const int m0  = mt * 128;
    const int nb  = nc * 128;

    const int rsel = l & 15;
    const int ksel = (l >> 4) * 8;
    const int s0   = 2 * w;
    const int wr   = w >> 1, wc = w & 1;

    const size_t aA0 = (size_t)(m0 + s0 * 16 + rsel) * 768 + ksel;
    const size_t aA1 = aA0 + 16 * 768;
    // B fragment base: row = nb + wc*64 + ni*16 + rsel, col = ksel (+k0)
    const __bf16* bbh = w1t_hi + (size_t)(nb + wc * 64 + rsel) * 768 + ksel;
    const __bf16* bbl = w1t_lo + (size_t)(nb + wc * 64 + rsel) * 768 + ksel;

    f32x4 acc[4][4];
    #pragma unroll
    for (int i = 0; i < 4; ++i)
        #pragma unroll
        for (int j = 0; j < 4; ++j) acc[i][j] = (f32x4){0.f, 0.f, 0.f, 0.f};

    auto stage = [&](int buf, int k0) {
        GL2LDS16(a_hi + aA0 + k0, &sAh[buf][s0][0]);
        GL2LDS16(a_hi + aA1 + k0, &sAh[buf][s0 + 1][0]);
        GL2LDS16(a_lo + aA0 + k0, &sAl[buf][s0][0]);
        GL2LDS16(a_lo + aA1 + k0, &sAl[buf][s0 + 1][0]);
    };

    stage(0, 0);

    for (int kt = 0; kt < 24; ++kt) {
        const int cur = kt & 1;
        const int k0  = kt * 32;
        __syncthreads();                       // stage(cur) complete; prior reads done
        if (kt < 23) stage(cur ^ 1, k0 + 32);

        // B fragments straight from global (w1t is 3MB -> L2-resident)
        bf16x8 bh[4], bl[4];
        #pragma unroll
        for (int ni = 0; ni < 4; ++ni) {
            bh[ni] = *(const bf16x8*)(bbh + (size_t)ni * 16 * 768 + k0);
            bl[ni] = *(const bf16x8*)(bbl + (size_t)ni * 16 * 768 + k0);
        }
        bf16x8 ah[4], al[4];
        #pragma unroll
        for (int mi = 0; mi < 4; ++mi) {
            ah[mi] = *(const bf16x8*)&sAh[cur][wr * 4 + mi][l * 8];
            al[mi] = *(const bf16x8*)&sAl[cur][wr * 4 + mi][l * 8];
        }
        #pragma unroll
        for (int mi = 0; mi < 4; ++mi)
            #pragma unroll
            for (int ni = 0; ni < 4; ++ni) {
                acc[mi][ni] = __builtin_amdgcn_mfma_f32_16x16x32_bf16(ah[mi], bh[ni], acc[mi][ni], 0, 0, 0);
                acc[mi][ni] = __builtin_amdgcn_mfma_f32_16x16x32_bf16(al[mi], bh[ni], acc[mi][ni], 0, 0, 0);
                acc[mi][ni] = __builtin_amdgcn_mfma_f32_16x16x32_bf16(ah[mi], bl[ni], acc[mi][ni], 0, 0, 0);
            }
    }

    // epilogue: scores[row] += sum_col gelu(acc + b1[col]) * w2[col]
    // C/D frag: col = lane&15, row = (lane>>4)*4 + j
    const int colbase = nb + wc * 64 + (l & 15);
    const int rowg    = (l >> 4) * 4;
    #pragma unroll
    for (int mi = 0; mi < 4; ++mi) {
        float v[4] = {0.f, 0.f, 0.f, 0.f};
        #pragma unroll
        for (int ni = 0; ni < 4; ++ni) {
            int col = colbase + ni * 16;
            float b1v = b1[col], w2v = w2[col];
            #pragma unroll
            for (int j = 0; j < 4; ++j) {
                float x = acc[mi][ni][j] + b1v;
                float g = 0.5f * x * (1.0f + erff(x * 0.70710678118654752440f));
                v[j] = fmaf(g, w2v, v[j]);
            }
        }
        #pragma unroll
        for (int j = 0; j < 4; ++j) {
            v[j] += __shfl_xor(v[j], 1);
            v[j] += __shfl_xor(v[j], 2);
            v[j] += __shfl_xor(v[j], 4);
            v[j] += __shfl_xor(v[j], 8);
        }
        if ((l & 15) == 0) {
            int row = m0 + wr * 64 + mi * 16 + rowg;
            #pragma unroll
            for (int j = 0; j < 4; ++j) atomicAdd(&scores[row + j], v[j]);
        }
    }
}

// ---------------- 4a. per-batch masked mean/var/T_eff of scores ----------------
__global__ __launch_bounds__(256) void stats_kernel(
    const float* __restrict__ scores, const int* __restrict__ attn,
    float* __restrict__ stat)  // [0..31]=mean [32..63]=rinv [64..95]=teff
{
    __shared__ float red4[4];
    const int b = blockIdx.x, tid = threadIdx.x;
    float sv[4], av[4];
    float sa = 0.f, ss = 0.f;
    #pragma unroll
    for (int e = 0; e < 4; ++e) {
        int i = tid + 256 * e;
        float af = (float)attn[b * 1024 + i];
        float s  = (af != 0.f) ? scores[b * 1024 + i] : 0.f;
        av[e] = af; sv[e] = s;
        sa += af; ss += s;
    }
    float tot_a = block_reduce_sum_256(sa, red4);
    float tot_s = block_reduce_sum_256(ss, red4);
    float denom = fmaxf(tot_a, 1.0f);
    float mean  = tot_s / denom;
    float q = 0.f;
    #pragma unroll
    for (int e = 0; e < 4; ++e) { float d = sv[e] - mean; q += d * d * av[e]; }
    float tot_q = block_reduce_sum_256(q, red4);
    if (tid == 0) {
        stat[b]      = mean;
        stat[32 + b] = 1.0f / sqrtf(tot_q / denom + 1e-6f);
        stat[64 + b] = tot_a;
    }
}

// ---------------- 4b. ranks + pos (pos folded into the O(T^2) loop) -----------
// rank_j is strictly increasing in sn_j, so argsort(ranks) == order by
// (active first by sn asc, ties by index; padded last by index) — exactly the
// comparator counted here. 256 blocks = 32 b x 8 q-chunks; i-loop split over 2
// thread-halves, combined in LDS.
__global__ __launch_bounds__(256) void rank_kernel(
    const float* __restrict__ scores, const int* __restrict__ attn,
    const float* __restrict__ stat, float* __restrict__ ranks,
    int* __restrict__ pos)
{
    __shared__ float sn[1024];
    __shared__ float afs[1024];
    __shared__ double dsum[256];
    __shared__ int    csum[256];
    const int b = blockIdx.x >> 3, q = blockIdx.x & 7;
    const int tid = threadIdx.x;
    const float mean = stat[b], rinv = stat[32 + b];
    #pragma unroll
    for (int e = 0; e < 4; ++e) {
        int i = tid + 256 * e;
        float af = (float)attn[b * 1024 + i];
        float s  = (af != 0.f) ? scores[b * 1024 + i] : 0.f;
        sn[i]  = (s - mean) * rinv;
        afs[i] = af;
    }
    __syncthreads();
    const int jj   = tid & 127;
    const int half = tid >> 7;
    const int j    = q * 128 + jj;
    const float sj = sn[j];
    const bool  aj = (afs[j] != 0.f);
    double sum = 0.0;
    int    cnt = 0;
    const int i0 = half * 512;
    #pragma unroll 4
    for (int i = i0; i < i0 + 512; ++i) {
        float si = sn[i];
        float ai = afs[i];
        float d   = (sj - si) * 20.0f;   // 1/tau
        float ee  = expf(-fabsf(d));
        float rcp = 1.0f / (1.0f + ee);
        float sig = (d >= 0.f) ? rcp : ee * rcp;
        sum += (double)(sig * sig);
        bool c;
        if (ai != 0.f) c = aj ? (si < sj || (si == sj && i < j)) : true;
        else           c = aj ? false : (i < j);
        cnt += c ? 1 : 0;
    }
    dsum[tid] = sum; csum[tid] = cnt;
    __syncthreads();
    if (tid < 128) {
        double s2 = dsum[tid] + dsum[tid + 128];
        int    c2 = csum[tid] + csum[tid + 128];
        int gj = b * 1024 + q * 128 + tid;
        ranks[gj] = (afs[q * 128 + tid] == 0.f) ? 1e9f : (float)(1.0 + s2);
        pos[gj]   = c2;
    }
}

// ---------------- 4c. gates + g_soft + hard_mask + rho_eff (pos precomputed) --
__global__ __launch_bounds__(256) void gate_kernel(
    const float* __restrict__ ranks, const int* __restrict__ attn,
    const float* __restrict__ stat, const int* __restrict__ pos,
    float* __restrict__ w_rho, float* __restrict__ keff, float* __restrict__ out)
{
    __shared__ float red4[4];
    const int b = blockIdx.x, tid = threadIdx.x;
    const float teff = stat[64 + b];
    float rj[4], afj[4];
    int pj[4];
    #pragma unroll
    for (int e = 0; e < 4; ++e) {
        int j = tid + 256 * e;
        rj[e]  = ranks[b * 1024 + j];
        afj[e] = (float)attn[b * 1024 + j];
        pj[e]  = pos[b * 1024 + j];
    }
    const float rhos[3] = {0.1f, 0.25f, 0.5f};
    #pragma unroll 1
    for (int r = 0; r < 3; ++r) {
        float k = fmaxf(rintf(rhos[r] * teff), 1.0f);
        float gate[4]; float lsum = 0.f;
        #pragma unroll
        for (int e = 0; e < 4; ++e) {
            float d   = (k - rj[e]) / 0.2f;
            float ee  = expf(-fabsf(d));
            float rcp = 1.0f / (1.0f + ee);
            float sig = (d >= 0.f) ? rcp : ee * rcp;
            gate[e] = sig * afj[e];
            lsum += gate[e];
        }
        float gsum = block_reduce_sum_256(lsum, red4);
        float cl   = fmaxf(gsum, 1e-8f);
        float ls2  = 0.f;
        #pragma unroll
        for (int e = 0; e < 4; ++e) {
            int j = tid + 256 * e;
            float gs = gate[e] / cl * k;
            ls2 += gs;
            w_rho[r * BT + b * 1024 + j]     = gs;
            out[BT + r * BT + b * 1024 + j]  = ((float)pj[e] < k) ? 1.0f : 0.0f;
            if (r == 2) out[b * 1024 + j] = gs;
        }
        float ks = block_reduce_sum_256(ls2, red4);
        if (tid == 0) {
            keff[r * Bb + b] = ks;
            out[131076 + r * Bb + b] = ks / fmaxf(teff, 1.0f);
        }
    }
}

// ---------------- 5. pooling ----------------
__global__ __launch_bounds__(256) void pool_kernel(
    const int* __restrict__ ids, const int* __restrict__ attn,
    const float* __restrict__ emb_table, const float* __restrict__ w_rho,
    float* __restrict__ pacc)   // [4][32][768], slot 3 = full (attn weights)
{
    const int b = blockIdx.x >> 4, chunk = blockIdx.x & 15;
    const int tid = threadIdx.x;
    float accF[3] = {0,0,0}, acc0[3] = {0,0,0}, acc1[3] = {0,0,0}, acc2[3] = {0,0,0};
    const int t0 = chunk * 64;
    for (int t = t0; t < t0 + 64; ++t) {
        int gi = b * 1024 + t;
        if (attn[gi] == 0) continue;
        float w0 = w_rho[gi], wa = w_rho[BT + gi], wb = w_rho[2 * BT + gi];
        const float* row = emb_table + (size_t)ids[gi] * 768;
        #pragma unroll
        for (int e = 0; e < 3; ++e) {
            float v = row[tid + 256 * e];
            accF[e] += v;
            acc0[e] = fmaf(w0, v, acc0[e]);
            acc1[e] = fmaf(wa, v, acc1[e]);
            acc2[e] = fmaf(wb, v, acc2[e]);
        }
    }
    #pragma unroll
    for (int e = 0; e < 3; ++e) {
        int d = tid + 256 * e;
        atomicAdd(&pacc[(0 * Bb + b) * 768 + d], acc0[e]);
        atomicAdd(&pacc[(1 * Bb + b) * 768 + d], acc1[e]);
        atomicAdd(&pacc[(2 * Bb + b) * 768 + d], acc2[e]);
        atomicAdd(&pacc[(3 * Bb + b) * 768 + d], accF[e]);
    }
}

// ---------------- 6. losses + recon_avg ----------------
__global__ __launch_bounds__(256) void final_kernel(
    const float* __restrict__ pacc, const float* __restrict__ keff,
    const float* __restrict__ stat, float* __restrict__ out)
{
    __shared__ float red4[4];
    const int tid = threadIdx.x;
    float lsum[3];
    #pragma unroll 1
    for (int r = 0; r < 3; ++r) {
        float local = 0.f;
        for (int idx = tid; idx < Bb * 768; idx += 256) {
            int b = idx / 768;
            int d = idx - b * 768;
            float fullv = pacc[(3 * Bb + b) * 768 + d] / fmaxf(stat[64 + b], 1e-9f);
            float predv = pacc[(r * Bb + b) * 768 + d] / fmaxf(keff[r * Bb + b], 1e-9f);
            float df = predv - fullv;
            local += df * df;
        }
        float tot = block_reduce_sum_256(local, red4);
        lsum[r] = tot / 24576.0f;
    }
    if (tid == 0) {
        out[131073] = lsum[0];
        out[131074] = lsum[1];
        out[131075] = lsum[2];
        out[131072] = (lsum[0] + lsum[1] + lsum[2]) / 3.0f;
    }
}

// ---------------- launch ----------------
extern "C" void kernel_launch(void* const* d_in, const int* in_sizes, int n_in,
                              void* d_out, int out_size, void* d_ws, size_t ws_size,
                              hipStream_t stream) {
    const int*   ids       = (const int*)d_in[0];
    const float* emb       = (const float*)d_in[1];
    const int*   attn      = (const int*)d_in[2];
    const float* ln_g      = (const float*)d_in[3];
    const float* ln_b      = (const float*)d_in[4];
    const float* w1        = (const float*)d_in[5];
    const float* b1        = (const float*)d_in[6];
    const float* w2        = (const float*)d_in[7];
    const float* b2        = (const float*)d_in[8];
    const float* emb_table = (const float*)d_in[9];
    float* out = (float*)d_out;
    float* ws  = (float*)d_ws;

    float* scores = ws;                    // 32768
    float* ranks  = ws + 32768;            // 32768
    float* w_rho  = ws + 65536;            // 3*32768
    float* stat   = ws + 163840;           // 96
    float* keff   = ws + 163936;           // 96
    float* pacc   = ws + 164032;           // 98304 (ends 262336)
    int*   pos    = (int*)(ws + 262400);   // 32768 ints
    short* a_hi   = (short*)(ws + 295168);         // 16384*768 shorts
    short* a_lo   = a_hi + (size_t)HALF_M * 768;   // 16384*768 shorts
    short* w1t_hi = a_lo + (size_t)HALF_M * 768;   // 1024*768 shorts
    short* w1t_lo = w1t_hi + 1024 * 768;           // 1024*768 shorts

    hipMemsetAsync(pacc, 0, 98304 * sizeof(float), stream);
    init_scores_kernel<<<128, 256, 0, stream>>>(b2, scores);
    prep_w1t_kernel<<<384, 256, 0, stream>>>(w1, w1t_hi, w1t_lo);

    for (int h = 0; h < 2; ++h) {
        prep_a_kernel<<<4096, 256, 0, stream>>>(
            emb + (size_t)h * HALF_M * 768, attn + h * HALF_M, ln_g, ln_b, a_hi, a_lo);
        score_gemm_mfma<<<1024, 256, 0, stream>>>(
            (const __bf16*)a_hi, (const __bf16*)a_lo,
            (const __bf16*)w1t_hi, (const __bf16*)w1t_lo,
            b1, w2, scores + (size_t)h * HALF_M);
    }

    stats_kernel<<<32, 256, 0, stream>>>(scores, attn, stat);
    rank_kernel<<<256, 256, 0, stream>>>(scores, attn, stat, ranks, pos);
    gate_kernel<<<32, 256, 0, stream>>>(ranks, attn, stat, pos, w_rho, keff, out);
    pool_kernel<<<512, 256, 0, stream>>>(ids, attn, emb_table, w_rho, pacc);
    final_kernel<<<1, 256, 0, stream>>>(pacc, keff, stat, out);
}

// Round 4
// 399.484 us; speedup vs baseline: 2.3779x; 1.3686x over previous
//
#include <hip/hip_runtime.h>
#include <math.h>

#define BT 32768   // B*T
#define Dd 768
#define Hh 1024
#define Bb 32
#define Tt 1024
#define HALF_M 16384

typedef __bf16 bf16x8 __attribute__((ext_vector_type(8)));
typedef float f32x4 __attribute__((ext_vector_type(4)));

#define GL2LDS16(gp, lp) __builtin_amdgcn_global_load_lds( \
    (const __attribute__((address_space(1))) void*)(gp),   \
    (__attribute__((address_space(3))) void*)(lp), 16, 0, 0)

// ---------------- helpers ----------------
__device__ __forceinline__ float block_reduce_sum_256(float v, float* red4) {
    int tid = threadIdx.x;
    #pragma unroll
    for (int o = 32; o > 0; o >>= 1) v += __shfl_down(v, o);
    __syncthreads();
    if ((tid & 63) == 0) red4[tid >> 6] = v;
    __syncthreads();
    return red4[0] + red4[1] + red4[2] + red4[3];
}

__device__ __forceinline__ void bf16split(float x, short& h, short& l) {
    unsigned u = __float_as_uint(x);
    unsigned r = (u + 0x7FFFu + ((u >> 16) & 1u)) >> 16;     // RNE to bf16
    h = (short)r;
    float fh = __uint_as_float(r << 16);
    float lof = x - fh;
    unsigned u2 = __float_as_uint(lof);
    unsigned r2 = (u2 + 0x7FFFu + ((u2 >> 16) & 1u)) >> 16;
    l = (short)r2;
}

__device__ __forceinline__ int pack2(short a, short b) {
    return (int)(unsigned short)a | ((int)(unsigned short)b << 16);
}

// ---------------- 1. prep A: LN + bf16 hi/lo split (one wave per token) -------
__global__ __launch_bounds__(256) void prep_a_kernel(
    const float* __restrict__ emb, const int* __restrict__ attn,
    const float* __restrict__ ln_g, const float* __restrict__ ln_b,
    short* __restrict__ a_hi, short* __restrict__ a_lo)
{
    int tok  = blockIdx.x * 4 + (threadIdx.x >> 6);
    int lane = threadIdx.x & 63;
    float af = (float)attn[tok];
    const float4* row4 = (const float4*)(emb + (size_t)tok * Dd);
    float4 x[3];
    #pragma unroll
    for (int e = 0; e < 3; ++e) x[e] = row4[lane + 64 * e];
    float s = 0.f;
    #pragma unroll
    for (int e = 0; e < 3; ++e) {
        x[e].x *= af; x[e].y *= af; x[e].z *= af; x[e].w *= af;
        s += x[e].x + x[e].y + x[e].z + x[e].w;
    }
    #pragma unroll
    for (int o = 32; o > 0; o >>= 1) s += __shfl_down(s, o);
    s = __shfl(s, 0);
    float mean = s / 768.0f;
    float q = 0.f;
    #pragma unroll
    for (int e = 0; e < 3; ++e) {
        float d0 = x[e].x - mean, d1 = x[e].y - mean, d2 = x[e].z - mean, d3 = x[e].w - mean;
        q += d0*d0 + d1*d1 + d2*d2 + d3*d3;
    }
    #pragma unroll
    for (int o = 32; o > 0; o >>= 1) q += __shfl_down(q, o);
    q = __shfl(q, 0);
    float rstd = 1.0f / sqrtf(q / 768.0f + 1e-5f);

    #pragma unroll
    for (int e = 0; e < 3; ++e) {
        int idx = lane * 4 + e * 256;
        float4 g4 = *(const float4*)(ln_g + idx);
        float4 b4 = *(const float4*)(ln_b + idx);
        float o0 = (x[e].x - mean) * rstd * g4.x + b4.x;
        float o1 = (x[e].y - mean) * rstd * g4.y + b4.y;
        float o2 = (x[e].z - mean) * rstd * g4.z + b4.z;
        float o3 = (x[e].w - mean) * rstd * g4.w + b4.w;
        short h0,h1,h2,h3,l0,l1,l2,l3;
        bf16split(o0,h0,l0); bf16split(o1,h1,l1);
        bf16split(o2,h2,l2); bf16split(o3,h3,l3);
        *(int2*)(a_hi + (size_t)tok * 768 + idx) = make_int2(pack2(h0,h1), pack2(h2,h3));
        *(int2*)(a_lo + (size_t)tok * 768 + idx) = make_int2(pack2(l0,l1), pack2(l2,l3));
    }
}

// ---------------- 2. prep W1^T: transpose + bf16 hi/lo split -------------------
__global__ __launch_bounds__(256) void prep_w1t_kernel(
    const float* __restrict__ w1, short* __restrict__ w1t_hi, short* __restrict__ w1t_lo)
{
    __shared__ float tile[32][65];
    const int kb  = blockIdx.x % 24;         // k block of 32
    const int nb0 = (blockIdx.x / 24) * 64;  // n block of 64
    const int tid = threadIdx.x;
    const int r0 = tid >> 6, c = tid & 63;
    #pragma unroll
    for (int rr = 0; rr < 8; ++rr) {
        int k = kb * 32 + r0 + rr * 4;
        tile[r0 + rr * 4][c] = w1[(size_t)k * 1024 + nb0 + c];
    }
    __syncthreads();
    const int n = tid >> 2, kc = (tid & 3) * 8;
    short h[8], lo[8];
    #pragma unroll
    for (int e = 0; e < 8; ++e) bf16split(tile[kc + e][n], h[e], lo[e]);
    size_t off = (size_t)(nb0 + n) * 768 + kb * 32 + kc;
    *(int4*)(w1t_hi + off) = make_int4(pack2(h[0],h[1]), pack2(h[2],h[3]),
                                       pack2(h[4],h[5]), pack2(h[6],h[7]));
    *(int4*)(w1t_lo + off) = make_int4(pack2(lo[0],lo[1]), pack2(lo[2],lo[3]),
                                       pack2(lo[4],lo[5]), pack2(lo[6],lo[7]));
}

// ---------------- 3a. init scores with b2 ----------------
__global__ void init_scores_kernel(const float* __restrict__ b2, float* __restrict__ scores) {
    int i = blockIdx.x * 256 + threadIdx.x;
    scores[i] = b2[0];
}

// ---------------- 3b. MFMA GEMM: 512 thr, 8 waves of 64x32, regs<128 ----------
// 128x128 tile, BK=32, dbuf LDS (64KB). Wave grid 2(wr) x 4(wc); per-wave acc
// 4x2 frags = 32 AGPR -> total regs ~110 < 128 -> 4 waves/SIMD (16 waves/CU).
__global__ __launch_bounds__(512, 4) void score_gemm_mfma(
    const __bf16* __restrict__ a_hi, const __bf16* __restrict__ a_lo,
    const __bf16* __restrict__ w1t_hi, const __bf16* __restrict__ w1t_lo,
    const float* __restrict__ b1, const float* __restrict__ w2,
    float* __restrict__ scores)
{
    __shared__ __align__(16) __bf16 sAh[2][8][512];
    __shared__ __align__(16) __bf16 sAl[2][8][512];
    __shared__ __align__(16) __bf16 sBh[2][8][512];
    __shared__ __align__(16) __bf16 sBl[2][8][512];

    const int tid = threadIdx.x;
    const int l   = tid & 63;
    const int w   = tid >> 6;            // 0..7
    const int mt  = blockIdx.x & 127;
    const int nc  = blockIdx.x >> 7;
    const int m0  = mt * 128;
    const int nb  = nc * 128;

    const int rsel = l & 15;
    const int ksel = (l >> 4) * 8;
    const int wr   = w >> 2, wc = w & 3;  // 2 x 4 wave grid

    // staging: wave w covers 16-row group w of each array
    const size_t aA = (size_t)(m0 + w * 16 + rsel) * 768 + ksel;
    const size_t aB = (size_t)(nb + w * 16 + rsel) * 768 + ksel;

    f32x4 acc[4][2];
    #pragma unroll
    for (int i = 0; i < 4; ++i)
        #pragma unroll
        for (int j = 0; j < 2; ++j) acc[i][j] = (f32x4){0.f, 0.f, 0.f, 0.f};

    auto stage = [&](int buf, int k0) {
        GL2LDS16(a_hi   + aA + k0, &sAh[buf][w][0]);
        GL2LDS16(a_lo   + aA + k0, &sAl[buf][w][0]);
        GL2LDS16(w1t_hi + aB + k0, &sBh[buf][w][0]);
        GL2LDS16(w1t_lo + aB + k0, &sBl[buf][w][0]);
    };

    stage(0, 0);

    for (int kt = 0; kt < 24; ++kt) {
        const int cur = kt & 1;
        __syncthreads();                       // stage(cur) landed; prior reads done
        if (kt < 23) stage(cur ^ 1, (kt + 1) * 32);

        bf16x8 ah[4], al[4], bh[2], bl[2];
        #pragma unroll
        for (int mi = 0; mi < 4; ++mi) {
            ah[mi] = *(const bf16x8*)&sAh[cur][wr * 4 + mi][l * 8];
            al[mi] = *(const bf16x8*)&sAl[cur][wr * 4 + mi][l * 8];
        }
        #pragma unroll
        for (int ni = 0; ni < 2; ++ni) {
            bh[ni] = *(const bf16x8*)&sBh[cur][wc * 2 + ni][l * 8];
            bl[ni] = *(const bf16x8*)&sBl[cur][wc * 2 + ni][l * 8];
        }
        // break dependent chains: all hh first, then lh, then hl
        #pragma unroll
        for (int mi = 0; mi < 4; ++mi)
            #pragma unroll
            for (int ni = 0; ni < 2; ++ni)
                acc[mi][ni] = __builtin_amdgcn_mfma_f32_16x16x32_bf16(ah[mi], bh[ni], acc[mi][ni], 0, 0, 0);
        #pragma unroll
        for (int mi = 0; mi < 4; ++mi)
            #pragma unroll
            for (int ni = 0; ni < 2; ++ni)
                acc[mi][ni] = __builtin_amdgcn_mfma_f32_16x16x32_bf16(al[mi], bh[ni], acc[mi][ni], 0, 0, 0);
        #pragma unroll
        for (int mi = 0; mi < 4; ++mi)
            #pragma unroll
            for (int ni = 0; ni < 2; ++ni)
                acc[mi][ni] = __builtin_amdgcn_mfma_f32_16x16x32_bf16(ah[mi], bl[ni], acc[mi][ni], 0, 0, 0);
    }

    // epilogue: scores[row] += sum_col gelu(acc + b1[col]) * w2[col]
    // C/D frag: col = lane&15, row = (lane>>4)*4 + j
    const int colbase = nb + wc * 32 + (l & 15);
    const int rowg    = (l >> 4) * 4;
    #pragma unroll
    for (int mi = 0; mi < 4; ++mi) {
        float v[4] = {0.f, 0.f, 0.f, 0.f};
        #pragma unroll
        for (int ni = 0; ni < 2; ++ni) {
            int col = colbase + ni * 16;
            float b1v = b1[col], w2v = w2[col];
            #pragma unroll
            for (int j = 0; j < 4; ++j) {
                float x = acc[mi][ni][j] + b1v;
                float g = 0.5f * x * (1.0f + erff(x * 0.70710678118654752440f));
                v[j] = fmaf(g, w2v, v[j]);
            }
        }
        #pragma unroll
        for (int j = 0; j < 4; ++j) {
            v[j] += __shfl_xor(v[j], 1);
            v[j] += __shfl_xor(v[j], 2);
            v[j] += __shfl_xor(v[j], 4);
            v[j] += __shfl_xor(v[j], 8);
        }
        if ((l & 15) == 0) {
            int row = m0 + wr * 64 + mi * 16 + rowg;
            #pragma unroll
            for (int j = 0; j < 4; ++j) atomicAdd(&scores[row + j], v[j]);
        }
    }
}

// ---------------- 4a. per-batch masked mean/var/T_eff of scores ----------------
__global__ __launch_bounds__(256) void stats_kernel(
    const float* __restrict__ scores, const int* __restrict__ attn,
    float* __restrict__ stat)  // [0..31]=mean [32..63]=rinv [64..95]=teff
{
    __shared__ float red4[4];
    const int b = blockIdx.x, tid = threadIdx.x;
    float sv[4], av[4];
    float sa = 0.f, ss = 0.f;
    #pragma unroll
    for (int e = 0; e < 4; ++e) {
        int i = tid + 256 * e;
        float af = (float)attn[b * 1024 + i];
        float s  = (af != 0.f) ? scores[b * 1024 + i] : 0.f;
        av[e] = af; sv[e] = s;
        sa += af; ss += s;
    }
    float tot_a = block_reduce_sum_256(sa, red4);
    float tot_s = block_reduce_sum_256(ss, red4);
    float denom = fmaxf(tot_a, 1.0f);
    float mean  = tot_s / denom;
    float q = 0.f;
    #pragma unroll
    for (int e = 0; e < 4; ++e) { float d = sv[e] - mean; q += d * d * av[e]; }
    float tot_q = block_reduce_sum_256(q, red4);
    if (tid == 0) {
        stat[b]      = mean;
        stat[32 + b] = 1.0f / sqrtf(tot_q / denom + 1e-6f);
        stat[64 + b] = tot_a;
    }
}

// ---------------- 4b. ranks + pos (pos folded into the O(T^2) loop) -----------
__global__ __launch_bounds__(256) void rank_kernel(
    const float* __restrict__ scores, const int* __restrict__ attn,
    const float* __restrict__ stat, float* __restrict__ ranks,
    int* __restrict__ pos)
{
    __shared__ float sn[1024];
    __shared__ float afs[1024];
    __shared__ double dsum[256];
    __shared__ int    csum[256];
    const int b = blockIdx.x >> 3, q = blockIdx.x & 7;
    const int tid = threadIdx.x;
    const float mean = stat[b], rinv = stat[32 + b];
    #pragma unroll
    for (int e = 0; e < 4; ++e) {
        int i = tid + 256 * e;
        float af = (float)attn[b * 1024 + i];
        float s  = (af != 0.f) ? scores[b * 1024 + i] : 0.f;
        sn[i]  = (s - mean) * rinv;
        afs[i] = af;
    }
    __syncthreads();
    const int jj   = tid & 127;
    const int half = tid >> 7;
    const int j    = q * 128 + jj;
    const float sj = sn[j];
    const bool  aj = (afs[j] != 0.f);
    double sum = 0.0;
    int    cnt = 0;
    const int i0 = half * 512;
    #pragma unroll 4
    for (int i = i0; i < i0 + 512; ++i) {
        float si = sn[i];
        float ai = afs[i];
        float d   = (sj - si) * 20.0f;   // 1/tau
        float ee  = expf(-fabsf(d));
        float rcp = 1.0f / (1.0f + ee);
        float sig = (d >= 0.f) ? rcp : ee * rcp;
        sum += (double)(sig * sig);
        bool c;
        if (ai != 0.f) c = aj ? (si < sj || (si == sj && i < j)) : true;
        else           c = aj ? false : (i < j);
        cnt += c ? 1 : 0;
    }
    dsum[tid] = sum; csum[tid] = cnt;
    __syncthreads();
    if (tid < 128) {
        double s2 = dsum[tid] + dsum[tid + 128];
        int    c2 = csum[tid] + csum[tid + 128];
        int gj = b * 1024 + q * 128 + tid;
        ranks[gj] = (afs[q * 128 + tid] == 0.f) ? 1e9f : (float)(1.0 + s2);
        pos[gj]   = c2;
    }
}

// ---------------- 4c. gates + g_soft + hard_mask + rho_eff --------------------
__global__ __launch_bounds__(256) void gate_kernel(
    const float* __restrict__ ranks, const int* __restrict__ attn,
    const float* __restrict__ stat, const int* __restrict__ pos,
    float* __restrict__ w_rho, float* __restrict__ keff, float* __restrict__ out)
{
    __shared__ float red4[4];
    const int b = blockIdx.x, tid = threadIdx.x;
    const float teff = stat[64 + b];
    float rj[4], afj[4];
    int pj[4];
    #pragma unroll
    for (int e = 0; e < 4; ++e) {
        int j = tid + 256 * e;
        rj[e]  = ranks[b * 1024 + j];
        afj[e] = (float)attn[b * 1024 + j];
        pj[e]  = pos[b * 1024 + j];
    }
    const float rhos[3] = {0.1f, 0.25f, 0.5f};
    #pragma unroll 1
    for (int r = 0; r < 3; ++r) {
        float k = fmaxf(rintf(rhos[r] * teff), 1.0f);
        float gate[4]; float lsum = 0.f;
        #pragma unroll
        for (int e = 0; e < 4; ++e) {
            float d   = (k - rj[e]) / 0.2f;
            float ee  = expf(-fabsf(d));
            float rcp = 1.0f / (1.0f + ee);
            float sig = (d >= 0.f) ? rcp : ee * rcp;
            gate[e] = sig * afj[e];
            lsum += gate[e];
        }
        float gsum = block_reduce_sum_256(lsum, red4);
        float cl   = fmaxf(gsum, 1e-8f);
        float ls2  = 0.f;
        #pragma unroll
        for (int e = 0; e < 4; ++e) {
            int j = tid + 256 * e;
            float gs = gate[e] / cl * k;
            ls2 += gs;
            w_rho[r * BT + b * 1024 + j]     = gs;
            out[BT + r * BT + b * 1024 + j]  = ((float)pj[e] < k) ? 1.0f : 0.0f;
            if (r == 2) out[b * 1024 + j] = gs;
        }
        float ks = block_reduce_sum_256(ls2, red4);
        if (tid == 0) {
            keff[r * Bb + b] = ks;
            out[131076 + r * Bb + b] = ks / fmaxf(teff, 1.0f);
        }
    }
}

// ---------------- 5. pooling ----------------
__global__ __launch_bounds__(256) void pool_kernel(
    const int* __restrict__ ids, const int* __restrict__ attn,
    const float* __restrict__ emb_table, const float* __restrict__ w_rho,
    float* __restrict__ pacc)   // [4][32][768], slot 3 = full (attn weights)
{
    const int b = blockIdx.x >> 4, chunk = blockIdx.x & 15;
    const int tid = threadIdx.x;
    float accF[3] = {0,0,0}, acc0[3] = {0,0,0}, acc1[3] = {0,0,0}, acc2[3] = {0,0,0};
    const int t0 = chunk * 64;
    for (int t = t0; t < t0 + 64; ++t) {
        int gi = b * 1024 + t;
        if (attn[gi] == 0) continue;
        float w0 = w_rho[gi], wa = w_rho[BT + gi], wb = w_rho[2 * BT + gi];
        const float* row = emb_table + (size_t)ids[gi] * 768;
        #pragma unroll
        for (int e = 0; e < 3; ++e) {
            float v = row[tid + 256 * e];
            accF[e] += v;
            acc0[e] = fmaf(w0, v, acc0[e]);
            acc1[e] = fmaf(wa, v, acc1[e]);
            acc2[e] = fmaf(wb, v, acc2[e]);
        }
    }
    #pragma unroll
    for (int e = 0; e < 3; ++e) {
        int d = tid + 256 * e;
        atomicAdd(&pacc[(0 * Bb + b) * 768 + d], acc0[e]);
        atomicAdd(&pacc[(1 * Bb + b) * 768 + d], acc1[e]);
        atomicAdd(&pacc[(2 * Bb + b) * 768 + d], acc2[e]);
        atomicAdd(&pacc[(3 * Bb + b) * 768 + d], accF[e]);
    }
}

// ---------------- 6a. per-rho loss (3 blocks) ----------------
__global__ __launch_bounds__(256) void final3_kernel(
    const float* __restrict__ pacc, const float* __restrict__ keff,
    const float* __restrict__ stat, float* __restrict__ lsum, float* __restrict__ out)
{
    __shared__ float red4[4];
    const int r = blockIdx.x, tid = threadIdx.x;
    float local = 0.f;
    for (int idx = tid; idx < Bb * 768; idx += 256) {
        int b = idx / 768;
        int d = idx - b * 768;
        float fullv = pacc[(3 * Bb + b) * 768 + d] / fmaxf(stat[64 + b], 1e-9f);
        float predv = pacc[(r * Bb + b) * 768 + d] / fmaxf(keff[r * Bb + b], 1e-9f);
        float df = predv - fullv;
        local += df * df;
    }
    float tot = block_reduce_sum_256(local, red4);
    if (tid == 0) {
        float l = tot / 24576.0f;
        lsum[r] = l;
        out[131073 + r] = l;
    }
}

// ---------------- 6b. recon_avg ----------------
__global__ void final_avg_kernel(const float* __restrict__ lsum, float* __restrict__ out) {
    if (threadIdx.x == 0)
        out[131072] = (lsum[0] + lsum[1] + lsum[2]) / 3.0f;
}

// ---------------- launch ----------------
extern "C" void kernel_launch(void* const* d_in, const int* in_sizes, int n_in,
                              void* d_out, int out_size, void* d_ws, size_t ws_size,
                              hipStream_t stream) {
    const int*   ids       = (const int*)d_in[0];
    const float* emb       = (const float*)d_in[1];
    const int*   attn      = (const int*)d_in[2];
    const float* ln_g      = (const float*)d_in[3];
    const float* ln_b      = (const float*)d_in[4];
    const float* w1        = (const float*)d_in[5];
    const float* b1        = (const float*)d_in[6];
    const float* w2        = (const float*)d_in[7];
    const float* b2        = (const float*)d_in[8];
    const float* emb_table = (const float*)d_in[9];
    float* out = (float*)d_out;
    float* ws  = (float*)d_ws;

    float* scores = ws;                    // 32768
    float* ranks  = ws + 32768;            // 32768
    float* w_rho  = ws + 65536;            // 3*32768
    float* stat   = ws + 163840;           // 96
    float* keff   = ws + 163936;           // 96
    float* lsum   = ws + 164032;           // 16
    float* pacc   = ws + 164048;           // 98304 (ends 262352)
    int*   pos    = (int*)(ws + 262400);   // 32768 ints (ends 295168)
    short* a_hi   = (short*)(ws + 295168);         // 16384*768 shorts
    short* a_lo   = a_hi + (size_t)HALF_M * 768;   // 16384*768 shorts
    short* w1t_hi = a_lo + (size_t)HALF_M * 768;   // 1024*768 shorts
    short* w1t_lo = w1t_hi + 1024 * 768;           // 1024*768 shorts

    hipMemsetAsync(pacc, 0, 98304 * sizeof(float), stream);
    init_scores_kernel<<<128, 256, 0, stream>>>(b2, scores);
    prep_w1t_kernel<<<384, 256, 0, stream>>>(w1, w1t_hi, w1t_lo);

    for (int h = 0; h < 2; ++h) {
        prep_a_kernel<<<4096, 256, 0, stream>>>(
            emb + (size_t)h * HALF_M * 768, attn + h * HALF_M, ln_g, ln_b, a_hi, a_lo);
        score_gemm_mfma<<<1024, 512, 0, stream>>>(
            (const __bf16*)a_hi, (const __bf16*)a_lo,
            (const __bf16*)w1t_hi, (const __bf16*)w1t_lo,
            b1, w2, scores + (size_t)h * HALF_M);
    }

    stats_kernel<<<32, 256, 0, stream>>>(scores, attn, stat);
    rank_kernel<<<256, 256, 0, stream>>>(scores, attn, stat, ranks, pos);
    gate_kernel<<<32, 256, 0, stream>>>(ranks, attn, stat, pos, w_rho, keff, out);
    pool_kernel<<<512, 256, 0, stream>>>(ids, attn, emb_table, w_rho, pacc);
    final3_kernel<<<3, 256, 0, stream>>>(pacc, keff, stat, lsum, out);
    final_avg_kernel<<<1, 64, 0, stream>>>(lsum, out);
}

// Round 5
// 326.655 us; speedup vs baseline: 2.9081x; 1.2230x over previous
//
#include <hip/hip_runtime.h>
#include <math.h>

#define BT 32768   // B*T
#define Dd 768
#define Hh 1024
#define Bb 32
#define Tt 1024
#define HALF_M 16384

typedef __bf16 bf16x8 __attribute__((ext_vector_type(8)));
typedef float f32x4 __attribute__((ext_vector_type(4)));

#define GL2LDS16(gp, lp) __builtin_amdgcn_global_load_lds( \
    (const __attribute__((address_space(1))) void*)(gp),   \
    (__attribute__((address_space(3))) void*)(lp), 16, 0, 0)

// ---------------- helpers ----------------
__device__ __forceinline__ float block_reduce_sum_256(float v, float* red4) {
    int tid = threadIdx.x;
    #pragma unroll
    for (int o = 32; o > 0; o >>= 1) v += __shfl_down(v, o);
    __syncthreads();
    if ((tid & 63) == 0) red4[tid >> 6] = v;
    __syncthreads();
    return red4[0] + red4[1] + red4[2] + red4[3];
}

__device__ __forceinline__ void bf16split(float x, short& h, short& l) {
    unsigned u = __float_as_uint(x);
    unsigned r = (u + 0x7FFFu + ((u >> 16) & 1u)) >> 16;     // RNE to bf16
    h = (short)r;
    float fh = __uint_as_float(r << 16);
    float lof = x - fh;
    unsigned u2 = __float_as_uint(lof);
    unsigned r2 = (u2 + 0x7FFFu + ((u2 >> 16) & 1u)) >> 16;
    l = (short)r2;
}

__device__ __forceinline__ int pack2(short a, short b) {
    return (int)(unsigned short)a | ((int)(unsigned short)b << 16);
}

// ---------------- 0a. per-256-token-segment active counts ----------------
__global__ __launch_bounds__(256) void seg_count_kernel(
    const int* __restrict__ attn, int* __restrict__ segsum)
{
    const int tid = threadIdx.x;
    int a = (attn[blockIdx.x * 256 + tid] != 0) ? 1 : 0;
    #pragma unroll
    for (int o = 32; o > 0; o >>= 1) a += __shfl_down(a, o);
    __shared__ int w4[4];
    if ((tid & 63) == 0) w4[tid >> 6] = a;
    __syncthreads();
    if (tid == 0) segsum[blockIdx.x] = w4[0] + w4[1] + w4[2] + w4[3];
}

// ---------------- 0b. serial scan of 128 segments (half-reset at 64) ----------
__global__ void seg_scan_kernel(const int* __restrict__ segsum,
                                int* __restrict__ seg_base, int* __restrict__ mh)
{
    if (threadIdx.x == 0) {
        int run = 0;
        for (int s = 0; s < 128; ++s) {
            if (s == 64) { mh[0] = run; run = 0; }
            seg_base[s] = run;
            run += segsum[s];
        }
        mh[1] = run;
    }
}

// ---------------- 0c. per-token compact row (ballot prefix) -------------------
__global__ __launch_bounds__(256) void cidx_kernel(
    const int* __restrict__ attn, const int* __restrict__ seg_base,
    int* __restrict__ row_of, int* __restrict__ tok_of)
{
    const int bid = blockIdx.x, tid = threadIdx.x;
    const int tok = bid * 256 + tid;
    const int active = (attn[tok] != 0) ? 1 : 0;
    unsigned long long m = __ballot(active);
    const int lane = tid & 63, wv = tid >> 6;
    __shared__ int wcnt[4];
    if (lane == 0) wcnt[wv] = __popcll(m);
    __syncthreads();
    int woff = 0;
    for (int q = 0; q < wv; ++q) woff += wcnt[q];
    int below = __popcll(m & ((1ULL << lane) - 1ULL));
    int row = seg_base[bid] + woff + below;          // row within half
    row_of[tok] = active ? row : -1;
    if (active) tok_of[(bid >> 6) * HALF_M + row] = tok;   // global token id
}

// ---------------- 1. prep A (per half): LN + bf16 hi/lo split, compacted ------
__global__ __launch_bounds__(256) void prep_a_kernel(
    const float* __restrict__ emb, const int* __restrict__ attn,
    const int* __restrict__ row_of,
    const float* __restrict__ ln_g, const float* __restrict__ ln_b,
    short* __restrict__ a_hi, short* __restrict__ a_lo)
{
    int tok  = blockIdx.x * 4 + (threadIdx.x >> 6);   // token within half
    int lane = threadIdx.x & 63;
    int av   = attn[tok];
    if (av == 0) return;                               // wave-uniform skip
    float af = (float)av;
    int row = row_of[tok];
    const float4* row4 = (const float4*)(emb + (size_t)tok * Dd);
    float4 x[3];
    #pragma unroll
    for (int e = 0; e < 3; ++e) x[e] = row4[lane + 64 * e];
    float s = 0.f;
    #pragma unroll
    for (int e = 0; e < 3; ++e) {
        x[e].x *= af; x[e].y *= af; x[e].z *= af; x[e].w *= af;
        s += x[e].x + x[e].y + x[e].z + x[e].w;
    }
    #pragma unroll
    for (int o = 32; o > 0; o >>= 1) s += __shfl_down(s, o);
    s = __shfl(s, 0);
    float mean = s / 768.0f;
    float q = 0.f;
    #pragma unroll
    for (int e = 0; e < 3; ++e) {
        float d0 = x[e].x - mean, d1 = x[e].y - mean, d2 = x[e].z - mean, d3 = x[e].w - mean;
        q += d0*d0 + d1*d1 + d2*d2 + d3*d3;
    }
    #pragma unroll
    for (int o = 32; o > 0; o >>= 1) q += __shfl_down(q, o);
    q = __shfl(q, 0);
    float rstd = 1.0f / sqrtf(q / 768.0f + 1e-5f);

    #pragma unroll
    for (int e = 0; e < 3; ++e) {
        int idx = lane * 4 + e * 256;
        float4 g4 = *(const float4*)(ln_g + idx);
        float4 b4 = *(const float4*)(ln_b + idx);
        float o0 = (x[e].x - mean) * rstd * g4.x + b4.x;
        float o1 = (x[e].y - mean) * rstd * g4.y + b4.y;
        float o2 = (x[e].z - mean) * rstd * g4.z + b4.z;
        float o3 = (x[e].w - mean) * rstd * g4.w + b4.w;
        short h0,h1,h2,h3,l0,l1,l2,l3;
        bf16split(o0,h0,l0); bf16split(o1,h1,l1);
        bf16split(o2,h2,l2); bf16split(o3,h3,l3);
        *(int2*)(a_hi + (size_t)row * 768 + idx) = make_int2(pack2(h0,h1), pack2(h2,h3));
        *(int2*)(a_lo + (size_t)row * 768 + idx) = make_int2(pack2(l0,l1), pack2(l2,l3));
    }
}

// ---------------- 2. prep W1^T: transpose + bf16 hi/lo split -------------------
__global__ __launch_bounds__(256) void prep_w1t_kernel(
    const float* __restrict__ w1, short* __restrict__ w1t_hi, short* __restrict__ w1t_lo)
{
    __shared__ float tile[32][65];
    const int kb  = blockIdx.x % 24;         // k block of 32
    const int nb0 = (blockIdx.x / 24) * 64;  // n block of 64
    const int tid = threadIdx.x;
    const int r0 = tid >> 6, c = tid & 63;
    #pragma unroll
    for (int rr = 0; rr < 8; ++rr) {
        int k = kb * 32 + r0 + rr * 4;
        tile[r0 + rr * 4][c] = w1[(size_t)k * 1024 + nb0 + c];
    }
    __syncthreads();
    const int n = tid >> 2, kc = (tid & 3) * 8;
    short h[8], lo[8];
    #pragma unroll
    for (int e = 0; e < 8; ++e) bf16split(tile[kc + e][n], h[e], lo[e]);
    size_t off = (size_t)(nb0 + n) * 768 + kb * 32 + kc;
    *(int4*)(w1t_hi + off) = make_int4(pack2(h[0],h[1]), pack2(h[2],h[3]),
                                       pack2(h[4],h[5]), pack2(h[6],h[7]));
    *(int4*)(w1t_lo + off) = make_int4(pack2(lo[0],lo[1]), pack2(lo[2],lo[3]),
                                       pack2(lo[4],lo[5]), pack2(lo[6],lo[7]));
}

// ---------------- 3a. init scores: b2 for active, 0 for padded ----------------
__global__ void init_scores_kernel(const float* __restrict__ b2,
                                   const int* __restrict__ attn,
                                   float* __restrict__ scores) {
    int i = blockIdx.x * 256 + threadIdx.x;
    scores[i] = (attn[i] != 0) ? b2[0] : 0.f;
}

// ---------------- 3b. MFMA GEMM on compacted rows ----------------------------
// grid = 128 mtiles x 8 nchunks per half (worst case); blocks with
// mt*128 >= Mh exit. 512 thr, 8 waves of 64x32, regs<128 -> 4 waves/SIMD.
__global__ __launch_bounds__(512, 4) void score_gemm_mfma(
    const __bf16* __restrict__ a_hi, const __bf16* __restrict__ a_lo,
    const __bf16* __restrict__ w1t_hi, const __bf16* __restrict__ w1t_lo,
    const float* __restrict__ b1, const float* __restrict__ w2,
    const int* __restrict__ mh, const int* __restrict__ tok_of,
    float* __restrict__ scores)
{
    const int Mh = mh[0];
    const int mt = blockIdx.x & 127;
    const int m0 = mt * 128;
    if (m0 >= Mh) return;

    __shared__ __align__(16) __bf16 sAh[2][8][512];
    __shared__ __align__(16) __bf16 sAl[2][8][512];
    __shared__ __align__(16) __bf16 sBh[2][8][512];
    __shared__ __align__(16) __bf16 sBl[2][8][512];

    const int tid = threadIdx.x;
    const int l   = tid & 63;
    const int w   = tid >> 6;            // 0..7
    const int nc  = blockIdx.x >> 7;
    const int nb  = nc * 128;

    const int rsel = l & 15;
    const int ksel = (l >> 4) * 8;
    const int wr   = w >> 2, wc = w & 3;  // 2 x 4 wave grid

    const size_t aA = (size_t)(m0 + w * 16 + rsel) * 768 + ksel;
    const size_t aB = (size_t)(nb + w * 16 + rsel) * 768 + ksel;

    f32x4 acc[4][2];
    #pragma unroll
    for (int i = 0; i < 4; ++i)
        #pragma unroll
        for (int j = 0; j < 2; ++j) acc[i][j] = (f32x4){0.f, 0.f, 0.f, 0.f};

    auto stage = [&](int buf, int k0) {
        GL2LDS16(a_hi   + aA + k0, &sAh[buf][w][0]);
        GL2LDS16(a_lo   + aA + k0, &sAl[buf][w][0]);
        GL2LDS16(w1t_hi + aB + k0, &sBh[buf][w][0]);
        GL2LDS16(w1t_lo + aB + k0, &sBl[buf][w][0]);
    };

    stage(0, 0);

    for (int kt = 0; kt < 24; ++kt) {
        const int cur = kt & 1;
        __syncthreads();                       // stage(cur) landed; prior reads done
        if (kt < 23) stage(cur ^ 1, (kt + 1) * 32);

        bf16x8 ah[4], al[4], bh[2], bl[2];
        #pragma unroll
        for (int mi = 0; mi < 4; ++mi) {
            ah[mi] = *(const bf16x8*)&sAh[cur][wr * 4 + mi][l * 8];
            al[mi] = *(const bf16x8*)&sAl[cur][wr * 4 + mi][l * 8];
        }
        #pragma unroll
        for (int ni = 0; ni < 2; ++ni) {
            bh[ni] = *(const bf16x8*)&sBh[cur][wc * 2 + ni][l * 8];
            bl[ni] = *(const bf16x8*)&sBl[cur][wc * 2 + ni][l * 8];
        }
        #pragma unroll
        for (int mi = 0; mi < 4; ++mi)
            #pragma unroll
            for (int ni = 0; ni < 2; ++ni)
                acc[mi][ni] = __builtin_amdgcn_mfma_f32_16x16x32_bf16(ah[mi], bh[ni], acc[mi][ni], 0, 0, 0);
        #pragma unroll
        for (int mi = 0; mi < 4; ++mi)
            #pragma unroll
            for (int ni = 0; ni < 2; ++ni)
                acc[mi][ni] = __builtin_amdgcn_mfma_f32_16x16x32_bf16(al[mi], bh[ni], acc[mi][ni], 0, 0, 0);
        #pragma unroll
        for (int mi = 0; mi < 4; ++mi)
            #pragma unroll
            for (int ni = 0; ni < 2; ++ni)
                acc[mi][ni] = __builtin_amdgcn_mfma_f32_16x16x32_bf16(ah[mi], bl[ni], acc[mi][ni], 0, 0, 0);
    }

    // epilogue: scores[tok_of[row]] += sum_col gelu(acc + b1[col]) * w2[col]
    const int colbase = nb + wc * 32 + (l & 15);
    const int rowg    = (l >> 4) * 4;
    #pragma unroll
    for (int mi = 0; mi < 4; ++mi) {
        float v[4] = {0.f, 0.f, 0.f, 0.f};
        #pragma unroll
        for (int ni = 0; ni < 2; ++ni) {
            int col = colbase + ni * 16;
            float b1v = b1[col], w2v = w2[col];
            #pragma unroll
            for (int j = 0; j < 4; ++j) {
                float x = acc[mi][ni][j] + b1v;
                float g = 0.5f * x * (1.0f + erff(x * 0.70710678118654752440f));
                v[j] = fmaf(g, w2v, v[j]);
            }
        }
        #pragma unroll
        for (int j = 0; j < 4; ++j) {
            v[j] += __shfl_xor(v[j], 1);
            v[j] += __shfl_xor(v[j], 2);
            v[j] += __shfl_xor(v[j], 4);
            v[j] += __shfl_xor(v[j], 8);
        }
        if ((l & 15) == 0) {
            int rowb = m0 + wr * 64 + mi * 16 + rowg;
            #pragma unroll
            for (int j = 0; j < 4; ++j) {
                int row = rowb + j;
                if (row < Mh) atomicAdd(&scores[tok_of[row]], v[j]);
            }
        }
    }
}

// ---------------- 4a. per-batch masked mean/var/T_eff of scores ----------------
__global__ __launch_bounds__(256) void stats_kernel(
    const float* __restrict__ scores, const int* __restrict__ attn,
    float* __restrict__ stat)  // [0..31]=mean [32..63]=rinv [64..95]=teff
{
    __shared__ float red4[4];
    const int b = blockIdx.x, tid = threadIdx.x;
    float sv[4], av[4];
    float sa = 0.f, ss = 0.f;
    #pragma unroll
    for (int e = 0; e < 4; ++e) {
        int i = tid + 256 * e;
        float af = (float)attn[b * 1024 + i];
        float s  = (af != 0.f) ? scores[b * 1024 + i] : 0.f;
        av[e] = af; sv[e] = s;
        sa += af; ss += s;
    }
    float tot_a = block_reduce_sum_256(sa, red4);
    float tot_s = block_reduce_sum_256(ss, red4);
    float denom = fmaxf(tot_a, 1.0f);
    float mean  = tot_s / denom;
    float q = 0.f;
    #pragma unroll
    for (int e = 0; e < 4; ++e) { float d = sv[e] - mean; q += d * d * av[e]; }
    float tot_q = block_reduce_sum_256(q, red4);
    if (tid == 0) {
        stat[b]      = mean;
        stat[32 + b] = 1.0f / sqrtf(tot_q / denom + 1e-6f);
        stat[64 + b] = tot_a;
    }
}

// ---------------- 4b. ranks + pos; 512 blocks (32 b x 16 chunks of 64 j) ------
__global__ __launch_bounds__(256) void rank_kernel(
    const float* __restrict__ scores, const int* __restrict__ attn,
    const float* __restrict__ stat, float* __restrict__ ranks,
    int* __restrict__ pos)
{
    __shared__ float sn[1024];
    __shared__ float afs[1024];
    __shared__ double dsum[256];
    __shared__ int    csum[256];
    const int b = blockIdx.x >> 4, qc = blockIdx.x & 15;
    const int tid = threadIdx.x;
    const float mean = stat[b], rinv = stat[32 + b];
    #pragma unroll
    for (int e = 0; e < 4; ++e) {
        int i = tid + 256 * e;
        float af = (float)attn[b * 1024 + i];
        float s  = (af != 0.f) ? scores[b * 1024 + i] : 0.f;
        sn[i]  = (s - mean) * rinv;
        afs[i] = af;
    }
    __syncthreads();
    const int jj = tid & 63;
    const int qt = tid >> 6;        // i-quarter 0..3
    const int j  = qc * 64 + jj;
    const float sj = sn[j];
    const bool  aj = (afs[j] != 0.f);
    double sum = 0.0;
    int    cnt = 0;
    const int i0 = qt * 256;
    #pragma unroll 4
    for (int i = i0; i < i0 + 256; ++i) {
        float si = sn[i];
        float ai = afs[i];
        float d   = (sj - si) * 20.0f;   // 1/tau
        float ee  = expf(-fabsf(d));
        float rcp = 1.0f / (1.0f + ee);
        float sig = (d >= 0.f) ? rcp : ee * rcp;
        sum += (double)(sig * sig);
        bool c;
        if (ai != 0.f) c = aj ? (si < sj || (si == sj && i < j)) : true;
        else           c = aj ? false : (i < j);
        cnt += c ? 1 : 0;
    }
    dsum[tid] = sum; csum[tid] = cnt;
    __syncthreads();
    if (tid < 64) {
        double s2 = dsum[tid] + dsum[tid + 64] + dsum[tid + 128] + dsum[tid + 192];
        int    c2 = csum[tid] + csum[tid + 64] + csum[tid + 128] + csum[tid + 192];
        int gj = b * 1024 + qc * 64 + tid;
        ranks[gj] = (afs[qc * 64 + tid] == 0.f) ? 1e9f : (float)(1.0 + s2);
        pos[gj]   = c2;
    }
}

// ---------------- 4c. gates + g_soft + hard_mask + rho_eff --------------------
__global__ __launch_bounds__(256) void gate_kernel(
    const float* __restrict__ ranks, const int* __restrict__ attn,
    const float* __restrict__ stat, const int* __restrict__ pos,
    float* __restrict__ w_rho, float* __restrict__ keff, float* __restrict__ out)
{
    __shared__ float red4[4];
    const int b = blockIdx.x, tid = threadIdx.x;
    const float teff = stat[64 + b];
    float rj[4], afj[4];
    int pj[4];
    #pragma unroll
    for (int e = 0; e < 4; ++e) {
        int j = tid + 256 * e;
        rj[e]  = ranks[b * 1024 + j];
        afj[e] = (float)attn[b * 1024 + j];
        pj[e]  = pos[b * 1024 + j];
    }
    const float rhos[3] = {0.1f, 0.25f, 0.5f};
    #pragma unroll 1
    for (int r = 0; r < 3; ++r) {
        float k = fmaxf(rintf(rhos[r] * teff), 1.0f);
        float gate[4]; float lsum = 0.f;
        #pragma unroll
        for (int e = 0; e < 4; ++e) {
            float d   = (k - rj[e]) / 0.2f;
            float ee  = expf(-fabsf(d));
            float rcp = 1.0f / (1.0f + ee);
            float sig = (d >= 0.f) ? rcp : ee * rcp;
            gate[e] = sig * afj[e];
            lsum += gate[e];
        }
        float gsum = block_reduce_sum_256(lsum, red4);
        float cl   = fmaxf(gsum, 1e-8f);
        float ls2  = 0.f;
        #pragma unroll
        for (int e = 0; e < 4; ++e) {
            int j = tid + 256 * e;
            float gs = gate[e] / cl * k;
            ls2 += gs;
            w_rho[r * BT + b * 1024 + j]     = gs;
            out[BT + r * BT + b * 1024 + j]  = ((float)pj[e] < k) ? 1.0f : 0.0f;
            if (r == 2) out[b * 1024 + j] = gs;
        }
        float ks = block_reduce_sum_256(ls2, red4);
        if (tid == 0) {
            keff[r * Bb + b] = ks;
            out[131076 + r * Bb + b] = ks / fmaxf(teff, 1.0f);
        }
    }
}

// ---------------- 5. pooling ----------------
__global__ __launch_bounds__(256) void pool_kernel(
    const int* __restrict__ ids, const int* __restrict__ attn,
    const float* __restrict__ emb_table, const float* __restrict__ w_rho,
    float* __restrict__ pacc)   // [4][32][768], slot 3 = full (attn weights)
{
    const int b = blockIdx.x >> 4, chunk = blockIdx.x & 15;
    const int tid = threadIdx.x;
    float accF[3] = {0,0,0}, acc0[3] = {0,0,0}, acc1[3] = {0,0,0}, acc2[3] = {0,0,0};
    const int t0 = chunk * 64;
    for (int t = t0; t < t0 + 64; ++t) {
        int gi = b * 1024 + t;
        if (attn[gi] == 0) continue;
        float w0 = w_rho[gi], wa = w_rho[BT + gi], wb = w_rho[2 * BT + gi];
        const float* row = emb_table + (size_t)ids[gi] * 768;
        #pragma unroll
        for (int e = 0; e < 3; ++e) {
            float v = row[tid + 256 * e];
            accF[e] += v;
            acc0[e] = fmaf(w0, v, acc0[e]);
            acc1[e] = fmaf(wa, v, acc1[e]);
            acc2[e] = fmaf(wb, v, acc2[e]);
        }
    }
    #pragma unroll
    for (int e = 0; e < 3; ++e) {
        int d = tid + 256 * e;
        atomicAdd(&pacc[(0 * Bb + b) * 768 + d], acc0[e]);
        atomicAdd(&pacc[(1 * Bb + b) * 768 + d], acc1[e]);
        atomicAdd(&pacc[(2 * Bb + b) * 768 + d], acc2[e]);
        atomicAdd(&pacc[(3 * Bb + b) * 768 + d], accF[e]);
    }
}

// ---------------- 6a. per-rho loss (3 blocks) ----------------
__global__ __launch_bounds__(256) void final3_kernel(
    const float* __restrict__ pacc, const float* __restrict__ keff,
    const float* __restrict__ stat, float* __restrict__ lsum, float* __restrict__ out)
{
    __shared__ float red4[4];
    const int r = blockIdx.x, tid = threadIdx.x;
    float local = 0.f;
    for (int idx = tid; idx < Bb * 768; idx += 256) {
        int b = idx / 768;
        int d = idx - b * 768;
        float fullv = pacc[(3 * Bb + b) * 768 + d] / fmaxf(stat[64 + b], 1e-9f);
        float predv = pacc[(r * Bb + b) * 768 + d] / fmaxf(keff[r * Bb + b], 1e-9f);
        float df = predv - fullv;
        local += df * df;
    }
    float tot = block_reduce_sum_256(local, red4);
    if (tid == 0) {
        float l = tot / 24576.0f;
        lsum[r] = l;
        out[131073 + r] = l;
    }
}

// ---------------- 6b. recon_avg ----------------
__global__ void final_avg_kernel(const float* __restrict__ lsum, float* __restrict__ out) {
    if (threadIdx.x == 0)
        out[131072] = (lsum[0] + lsum[1] + lsum[2]) / 3.0f;
}

// ---------------- launch ----------------
extern "C" void kernel_launch(void* const* d_in, const int* in_sizes, int n_in,
                              void* d_out, int out_size, void* d_ws, size_t ws_size,
                              hipStream_t stream) {
    const int*   ids       = (const int*)d_in[0];
    const float* emb       = (const float*)d_in[1];
    const int*   attn      = (const int*)d_in[2];
    const float* ln_g      = (const float*)d_in[3];
    const float* ln_b      = (const float*)d_in[4];
    const float* w1        = (const float*)d_in[5];
    const float* b1        = (const float*)d_in[6];
    const float* w2        = (const float*)d_in[7];
    const float* b2        = (const float*)d_in[8];
    const float* emb_table = (const float*)d_in[9];
    float* out = (float*)d_out;
    float* ws  = (float*)d_ws;

    float* scores = ws;                    // 32768
    float* ranks  = ws + 32768;            // 32768
    float* w_rho  = ws + 65536;            // 3*32768
    float* stat   = ws + 163840;           // 96
    float* keff   = ws + 163936;           // 96
    float* lsum   = ws + 164032;           // 16
    float* pacc   = ws + 164048;           // 98304 (ends 262352)
    int*   pos    = (int*)(ws + 262400);   // 32768
    int*   row_of = (int*)(ws + 295168);   // 32768
    int*   tok_of = (int*)(ws + 327936);   // 32768
    int*   segsum = (int*)(ws + 360704);   // 128
    int*   segbas = (int*)(ws + 360832);   // 128
    int*   mh     = (int*)(ws + 360960);   // 2
    short* a_hi   = (short*)(ws + 361216);         // 16384*768 shorts
    short* a_lo   = a_hi + (size_t)HALF_M * 768;   // 16384*768 shorts
    short* w1t_hi = a_lo + (size_t)HALF_M * 768;   // 1024*768 shorts
    short* w1t_lo = w1t_hi + 1024 * 768;           // 1024*768 shorts

    hipMemsetAsync(pacc, 0, 98304 * sizeof(float), stream);
    seg_count_kernel<<<128, 256, 0, stream>>>(attn, segsum);
    seg_scan_kernel<<<1, 64, 0, stream>>>(segsum, segbas, mh);
    cidx_kernel<<<128, 256, 0, stream>>>(attn, segbas, row_of, tok_of);
    init_scores_kernel<<<128, 256, 0, stream>>>(b2, attn, scores);
    prep_w1t_kernel<<<384, 256, 0, stream>>>(w1, w1t_hi, w1t_lo);

    for (int h = 0; h < 2; ++h) {
        prep_a_kernel<<<4096, 256, 0, stream>>>(
            emb + (size_t)h * HALF_M * 768, attn + h * HALF_M, row_of + h * HALF_M,
            ln_g, ln_b, a_hi, a_lo);
        score_gemm_mfma<<<1024, 512, 0, stream>>>(
            (const __bf16*)a_hi, (const __bf16*)a_lo,
            (const __bf16*)w1t_hi, (const __bf16*)w1t_lo,
            b1, w2, mh + h, tok_of + h * HALF_M, scores);
    }

    stats_kernel<<<32, 256, 0, stream>>>(scores, attn, stat);
    rank_kernel<<<512, 256, 0, stream>>>(scores, attn, stat, ranks, pos);
    gate_kernel<<<32, 256, 0, stream>>>(ranks, attn, stat, pos, w_rho, keff, out);
    pool_kernel<<<512, 256, 0, stream>>>(ids, attn, emb_table, w_rho, pacc);
    final3_kernel<<<3, 256, 0, stream>>>(pacc, keff, stat, lsum, out);
    final_avg_kernel<<<1, 64, 0, stream>>>(lsum, out);
}

// Round 6
// 323.826 us; speedup vs baseline: 2.9335x; 1.0087x over previous
//
#include <hip/hip_runtime.h>
#include <math.h>

#define BT 32768   // B*T
#define Dd 768
#define Hh 1024
#define Bb 32
#define Tt 1024
#define HALF_M 16384

typedef __bf16 bf16x8 __attribute__((ext_vector_type(8)));
typedef float f32x4 __attribute__((ext_vector_type(4)));

#define GL2LDS16(gp, lp) __builtin_amdgcn_global_load_lds( \
    (const __attribute__((address_space(1))) void*)(gp),   \
    (__attribute__((address_space(3))) void*)(lp), 16, 0, 0)

// ---------------- helpers ----------------
__device__ __forceinline__ float block_reduce_sum_256(float v, float* red4) {
    int tid = threadIdx.x;
    #pragma unroll
    for (int o = 32; o > 0; o >>= 1) v += __shfl_down(v, o);
    __syncthreads();
    if ((tid & 63) == 0) red4[tid >> 6] = v;
    __syncthreads();
    return red4[0] + red4[1] + red4[2] + red4[3];
}

__device__ __forceinline__ void bf16split(float x, short& h, short& l) {
    unsigned u = __float_as_uint(x);
    unsigned r = (u + 0x7FFFu + ((u >> 16) & 1u)) >> 16;     // RNE to bf16
    h = (short)r;
    float fh = __uint_as_float(r << 16);
    float lof = x - fh;
    unsigned u2 = __float_as_uint(lof);
    unsigned r2 = (u2 + 0x7FFFu + ((u2 >> 16) & 1u)) >> 16;
    l = (short)r2;
}

__device__ __forceinline__ int pack2(short a, short b) {
    return (int)(unsigned short)a | ((int)(unsigned short)b << 16);
}

// ---------------- 0a. per-256-token-segment active counts ----------------
__global__ __launch_bounds__(256) void seg_count_kernel(
    const int* __restrict__ attn, int* __restrict__ segsum)
{
    const int tid = threadIdx.x;
    int a = (attn[blockIdx.x * 256 + tid] != 0) ? 1 : 0;
    #pragma unroll
    for (int o = 32; o > 0; o >>= 1) a += __shfl_down(a, o);
    __shared__ int w4[4];
    if ((tid & 63) == 0) w4[tid >> 6] = a;
    __syncthreads();
    if (tid == 0) segsum[blockIdx.x] = w4[0] + w4[1] + w4[2] + w4[3];
}

// ---------------- 0b. parallel scan of 128 segments (wave = half) -------------
__global__ __launch_bounds__(128) void seg_scan_kernel(
    const int* __restrict__ segsum, int* __restrict__ seg_base, int* __restrict__ mh)
{
    const int tid = threadIdx.x;        // 0..127
    const int lane = tid & 63, w = tid >> 6;
    int v = segsum[tid];
    int s = v;
    #pragma unroll
    for (int o = 1; o < 64; o <<= 1) {
        int t = __shfl_up(s, o);
        if (lane >= o) s += t;
    }
    seg_base[tid] = s - v;              // exclusive within half
    if (lane == 63) mh[w] = s;          // active count per half
}

// ---------------- 0c. per-token compact row (ballot prefix) -------------------
__global__ __launch_bounds__(256) void cidx_kernel(
    const int* __restrict__ attn, const int* __restrict__ seg_base,
    int* __restrict__ row_of, int* __restrict__ tok_of)
{
    const int bid = blockIdx.x, tid = threadIdx.x;
    const int tok = bid * 256 + tid;
    const int active = (attn[tok] != 0) ? 1 : 0;
    unsigned long long m = __ballot(active);
    const int lane = tid & 63, wv = tid >> 6;
    __shared__ int wcnt[4];
    if (lane == 0) wcnt[wv] = __popcll(m);
    __syncthreads();
    int woff = 0;
    for (int q = 0; q < wv; ++q) woff += wcnt[q];
    int below = __popcll(m & ((1ULL << lane) - 1ULL));
    int row = seg_base[bid] + woff + below;          // row within half
    row_of[tok] = active ? row : -1;
    if (active) tok_of[(bid >> 6) * HALF_M + row] = tok;   // global token id
}

// ---------------- 1. prep A (per half): LN + bf16 hi/lo split, compacted ------
__global__ __launch_bounds__(256) void prep_a_kernel(
    const float* __restrict__ emb, const int* __restrict__ attn,
    const int* __restrict__ row_of,
    const float* __restrict__ ln_g, const float* __restrict__ ln_b,
    short* __restrict__ a_hi, short* __restrict__ a_lo)
{
    int tok  = blockIdx.x * 4 + (threadIdx.x >> 6);   // token within half
    int lane = threadIdx.x & 63;
    int av   = attn[tok];
    if (av == 0) return;                               // wave-uniform skip
    float af = (float)av;
    int row = row_of[tok];
    const float4* row4 = (const float4*)(emb + (size_t)tok * Dd);
    float4 x[3];
    #pragma unroll
    for (int e = 0; e < 3; ++e) x[e] = row4[lane + 64 * e];
    float s = 0.f;
    #pragma unroll
    for (int e = 0; e < 3; ++e) {
        x[e].x *= af; x[e].y *= af; x[e].z *= af; x[e].w *= af;
        s += x[e].x + x[e].y + x[e].z + x[e].w;
    }
    #pragma unroll
    for (int o = 32; o > 0; o >>= 1) s += __shfl_down(s, o);
    s = __shfl(s, 0);
    float mean = s / 768.0f;
    float q = 0.f;
    #pragma unroll
    for (int e = 0; e < 3; ++e) {
        float d0 = x[e].x - mean, d1 = x[e].y - mean, d2 = x[e].z - mean, d3 = x[e].w - mean;
        q += d0*d0 + d1*d1 + d2*d2 + d3*d3;
    }
    #pragma unroll
    for (int o = 32; o > 0; o >>= 1) q += __shfl_down(q, o);
    q = __shfl(q, 0);
    float rstd = 1.0f / sqrtf(q / 768.0f + 1e-5f);

    #pragma unroll
    for (int e = 0; e < 3; ++e) {
        int idx = lane * 4 + e * 256;
        float4 g4 = *(const float4*)(ln_g + idx);
        float4 b4 = *(const float4*)(ln_b + idx);
        float o0 = (x[e].x - mean) * rstd * g4.x + b4.x;
        float o1 = (x[e].y - mean) * rstd * g4.y + b4.y;
        float o2 = (x[e].z - mean) * rstd * g4.z + b4.z;
        float o3 = (x[e].w - mean) * rstd * g4.w + b4.w;
        short h0,h1,h2,h3,l0,l1,l2,l3;
        bf16split(o0,h0,l0); bf16split(o1,h1,l1);
        bf16split(o2,h2,l2); bf16split(o3,h3,l3);
        *(int2*)(a_hi + (size_t)row * 768 + idx) = make_int2(pack2(h0,h1), pack2(h2,h3));
        *(int2*)(a_lo + (size_t)row * 768 + idx) = make_int2(pack2(l0,l1), pack2(l2,l3));
    }
}

// ---------------- 2. prep W1^T: transpose + bf16 hi/lo split -------------------
__global__ __launch_bounds__(256) void prep_w1t_kernel(
    const float* __restrict__ w1, short* __restrict__ w1t_hi, short* __restrict__ w1t_lo)
{
    __shared__ float tile[32][65];
    const int kb  = blockIdx.x % 24;         // k block of 32
    const int nb0 = (blockIdx.x / 24) * 64;  // n block of 64
    const int tid = threadIdx.x;
    const int r0 = tid >> 6, c = tid & 63;
    #pragma unroll
    for (int rr = 0; rr < 8; ++rr) {
        int k = kb * 32 + r0 + rr * 4;
        tile[r0 + rr * 4][c] = w1[(size_t)k * 1024 + nb0 + c];
    }
    __syncthreads();
    const int n = tid >> 2, kc = (tid & 3) * 8;
    short h[8], lo[8];
    #pragma unroll
    for (int e = 0; e < 8; ++e) bf16split(tile[kc + e][n], h[e], lo[e]);
    size_t off = (size_t)(nb0 + n) * 768 + kb * 32 + kc;
    *(int4*)(w1t_hi + off) = make_int4(pack2(h[0],h[1]), pack2(h[2],h[3]),
                                       pack2(h[4],h[5]), pack2(h[6],h[7]));
    *(int4*)(w1t_lo + off) = make_int4(pack2(lo[0],lo[1]), pack2(lo[2],lo[3]),
                                       pack2(lo[4],lo[5]), pack2(lo[6],lo[7]));
}

// ---------------- 3a. init scores: b2 for active, 0 for padded ----------------
__global__ void init_scores_kernel(const float* __restrict__ b2,
                                   const int* __restrict__ attn,
                                   float* __restrict__ scores) {
    int i = blockIdx.x * 256 + threadIdx.x;
    scores[i] = (attn[i] != 0) ? b2[0] : 0.f;
}

// ---------------- 3b. MFMA GEMM on compacted rows, mt-major mapping ----------
// mt = bid>>3 (contiguous active prefix, dead tail), nc = bid&7 (B XCD-local).
// 512 thr, 8 waves of 64x32, regs<128 -> 4 waves/SIMD; LDS 64KB -> 2 blk/CU.
__global__ __launch_bounds__(512, 4) void score_gemm_mfma(
    const __bf16* __restrict__ a_hi, const __bf16* __restrict__ a_lo,
    const __bf16* __restrict__ w1t_hi, const __bf16* __restrict__ w1t_lo,
    const float* __restrict__ b1, const float* __restrict__ w2,
    const int* __restrict__ mh, const int* __restrict__ tok_of,
    float* __restrict__ scores)
{
    const int Mh = mh[0];
    const int mt = blockIdx.x >> 3;
    const int m0 = mt * 128;
    if (m0 >= Mh) return;

    __shared__ __align__(16) __bf16 sAh[2][8][512];
    __shared__ __align__(16) __bf16 sAl[2][8][512];
    __shared__ __align__(16) __bf16 sBh[2][8][512];
    __shared__ __align__(16) __bf16 sBl[2][8][512];

    const int tid = threadIdx.x;
    const int l   = tid & 63;
    const int w   = tid >> 6;            // 0..7
    const int nc  = blockIdx.x & 7;
    const int nb  = nc * 128;

    const int rsel = l & 15;
    const int ksel = (l >> 4) * 8;
    const int wr   = w >> 2, wc = w & 3;  // 2 x 4 wave grid

    const size_t aA = (size_t)(m0 + w * 16 + rsel) * 768 + ksel;
    const size_t aB = (size_t)(nb + w * 16 + rsel) * 768 + ksel;

    f32x4 acc[4][2];
    #pragma unroll
    for (int i = 0; i < 4; ++i)
        #pragma unroll
        for (int j = 0; j < 2; ++j) acc[i][j] = (f32x4){0.f, 0.f, 0.f, 0.f};

    auto stage = [&](int buf, int k0) {
        GL2LDS16(a_hi   + aA + k0, &sAh[buf][w][0]);
        GL2LDS16(a_lo   + aA + k0, &sAl[buf][w][0]);
        GL2LDS16(w1t_hi + aB + k0, &sBh[buf][w][0]);
        GL2LDS16(w1t_lo + aB + k0, &sBl[buf][w][0]);
    };

    stage(0, 0);

    for (int kt = 0; kt < 24; ++kt) {
        const int cur = kt & 1;
        __syncthreads();                       // stage(cur) landed; prior reads done
        if (kt < 23) stage(cur ^ 1, (kt + 1) * 32);

        bf16x8 ah[4], al[4], bh[2], bl[2];
        #pragma unroll
        for (int mi = 0; mi < 4; ++mi) {
            ah[mi] = *(const bf16x8*)&sAh[cur][wr * 4 + mi][l * 8];
            al[mi] = *(const bf16x8*)&sAl[cur][wr * 4 + mi][l * 8];
        }
        #pragma unroll
        for (int ni = 0; ni < 2; ++ni) {
            bh[ni] = *(const bf16x8*)&sBh[cur][wc * 2 + ni][l * 8];
            bl[ni] = *(const bf16x8*)&sBl[cur][wc * 2 + ni][l * 8];
        }
        #pragma unroll
        for (int mi = 0; mi < 4; ++mi)
            #pragma unroll
            for (int ni = 0; ni < 2; ++ni)
                acc[mi][ni] = __builtin_amdgcn_mfma_f32_16x16x32_bf16(ah[mi], bh[ni], acc[mi][ni], 0, 0, 0);
        #pragma unroll
        for (int mi = 0; mi < 4; ++mi)
            #pragma unroll
            for (int ni = 0; ni < 2; ++ni)
                acc[mi][ni] = __builtin_amdgcn_mfma_f32_16x16x32_bf16(al[mi], bh[ni], acc[mi][ni], 0, 0, 0);
        #pragma unroll
        for (int mi = 0; mi < 4; ++mi)
            #pragma unroll
            for (int ni = 0; ni < 2; ++ni)
                acc[mi][ni] = __builtin_amdgcn_mfma_f32_16x16x32_bf16(ah[mi], bl[ni], acc[mi][ni], 0, 0, 0);
    }

    // epilogue: scores[tok_of[row]] += sum_col gelu(acc + b1[col]) * w2[col]
    const int colbase = nb + wc * 32 + (l & 15);
    const int rowg    = (l >> 4) * 4;
    #pragma unroll
    for (int mi = 0; mi < 4; ++mi) {
        float v[4] = {0.f, 0.f, 0.f, 0.f};
        #pragma unroll
        for (int ni = 0; ni < 2; ++ni) {
            int col = colbase + ni * 16;
            float b1v = b1[col], w2v = w2[col];
            #pragma unroll
            for (int j = 0; j < 4; ++j) {
                float x = acc[mi][ni][j] + b1v;
                float g = 0.5f * x * (1.0f + erff(x * 0.70710678118654752440f));
                v[j] = fmaf(g, w2v, v[j]);
            }
        }
        #pragma unroll
        for (int j = 0; j < 4; ++j) {
            v[j] += __shfl_xor(v[j], 1);
            v[j] += __shfl_xor(v[j], 2);
            v[j] += __shfl_xor(v[j], 4);
            v[j] += __shfl_xor(v[j], 8);
        }
        if ((l & 15) == 0) {
            int rowb = m0 + wr * 64 + mi * 16 + rowg;
            #pragma unroll
            for (int j = 0; j < 4; ++j) {
                int row = rowb + j;
                if (row < Mh) atomicAdd(&scores[tok_of[row]], v[j]);
            }
        }
    }
}

// ---------------- 4a. per-batch masked mean/var/T_eff of scores ----------------
__global__ __launch_bounds__(256) void stats_kernel(
    const float* __restrict__ scores, const int* __restrict__ attn,
    float* __restrict__ stat)  // [0..31]=mean [32..63]=rinv [64..95]=teff
{
    __shared__ float red4[4];
    const int b = blockIdx.x, tid = threadIdx.x;
    float sv[4], av[4];
    float sa = 0.f, ss = 0.f;
    #pragma unroll
    for (int e = 0; e < 4; ++e) {
        int i = tid + 256 * e;
        float af = (float)attn[b * 1024 + i];
        float s  = (af != 0.f) ? scores[b * 1024 + i] : 0.f;
        av[e] = af; sv[e] = s;
        sa += af; ss += s;
    }
    float tot_a = block_reduce_sum_256(sa, red4);
    float tot_s = block_reduce_sum_256(ss, red4);
    float denom = fmaxf(tot_a, 1.0f);
    float mean  = tot_s / denom;
    float q = 0.f;
    #pragma unroll
    for (int e = 0; e < 4; ++e) { float d = sv[e] - mean; q += d * d * av[e]; }
    float tot_q = block_reduce_sum_256(q, red4);
    if (tid == 0) {
        stat[b]      = mean;
        stat[32 + b] = 1.0f / sqrtf(tot_q / denom + 1e-6f);
        stat[64 + b] = tot_a;
    }
}

// ---------------- 4b. ranks + pos; 512 blocks (32 b x 16 chunks of 64 j) ------
__global__ __launch_bounds__(256) void rank_kernel(
    const float* __restrict__ scores, const int* __restrict__ attn,
    const float* __restrict__ stat, float* __restrict__ ranks,
    int* __restrict__ pos)
{
    __shared__ float sn[1024];
    __shared__ float afs[1024];
    __shared__ double dsum[256];
    __shared__ int    csum[256];
    const int b = blockIdx.x >> 4, qc = blockIdx.x & 15;
    const int tid = threadIdx.x;
    const float mean = stat[b], rinv = stat[32 + b];
    #pragma unroll
    for (int e = 0; e < 4; ++e) {
        int i = tid + 256 * e;
        float af = (float)attn[b * 1024 + i];
        float s  = (af != 0.f) ? scores[b * 1024 + i] : 0.f;
        sn[i]  = (s - mean) * rinv;
        afs[i] = af;
    }
    __syncthreads();
    const int jj = tid & 63;
    const int qt = tid >> 6;        // i-quarter 0..3
    const int j  = qc * 64 + jj;
    const float sj = sn[j];
    const bool  aj = (afs[j] != 0.f);
    double sum = 0.0;
    int    cnt = 0;
    const int i0 = qt * 256;
    #pragma unroll 4
    for (int i = i0; i < i0 + 256; ++i) {
        float si = sn[i];
        float ai = afs[i];
        float d   = (sj - si) * 20.0f;   // 1/tau
        float ee  = expf(-fabsf(d));
        float rcp = 1.0f / (1.0f + ee);
        float sig = (d >= 0.f) ? rcp : ee * rcp;
        sum += (double)(sig * sig);
        bool c;
        if (ai != 0.f) c = aj ? (si < sj || (si == sj && i < j)) : true;
        else           c = aj ? false : (i < j);
        cnt += c ? 1 : 0;
    }
    dsum[tid] = sum; csum[tid] = cnt;
    __syncthreads();
    if (tid < 64) {
        double s2 = dsum[tid] + dsum[tid + 64] + dsum[tid + 128] + dsum[tid + 192];
        int    c2 = csum[tid] + csum[tid + 64] + csum[tid + 128] + csum[tid + 192];
        int gj = b * 1024 + qc * 64 + tid;
        ranks[gj] = (afs[qc * 64 + tid] == 0.f) ? 1e9f : (float)(1.0 + s2);
        pos[gj]   = c2;
    }
}

// ---------------- 4c. gates + g_soft + hard_mask + rho_eff --------------------
__global__ __launch_bounds__(256) void gate_kernel(
    const float* __restrict__ ranks, const int* __restrict__ attn,
    const float* __restrict__ stat, const int* __restrict__ pos,
    float* __restrict__ w_rho, float* __restrict__ keff, float* __restrict__ out)
{
    __shared__ float red4[4];
    const int b = blockIdx.x, tid = threadIdx.x;
    const float teff = stat[64 + b];
    float rj[4], afj[4];
    int pj[4];
    #pragma unroll
    for (int e = 0; e < 4; ++e) {
        int j = tid + 256 * e;
        rj[e]  = ranks[b * 1024 + j];
        afj[e] = (float)attn[b * 1024 + j];
        pj[e]  = pos[b * 1024 + j];
    }
    const float rhos[3] = {0.1f, 0.25f, 0.5f};
    #pragma unroll 1
    for (int r = 0; r < 3; ++r) {
        float k = fmaxf(rintf(rhos[r] * teff), 1.0f);
        float gate[4]; float lsum = 0.f;
        #pragma unroll
        for (int e = 0; e < 4; ++e) {
            float d   = (k - rj[e]) / 0.2f;
            float ee  = expf(-fabsf(d));
            float rcp = 1.0f / (1.0f + ee);
            float sig = (d >= 0.f) ? rcp : ee * rcp;
            gate[e] = sig * afj[e];
            lsum += gate[e];
        }
        float gsum = block_reduce_sum_256(lsum, red4);
        float cl   = fmaxf(gsum, 1e-8f);
        float ls2  = 0.f;
        #pragma unroll
        for (int e = 0; e < 4; ++e) {
            int j = tid + 256 * e;
            float gs = gate[e] / cl * k;
            ls2 += gs;
            w_rho[r * BT + b * 1024 + j]     = gs;
            out[BT + r * BT + b * 1024 + j]  = ((float)pj[e] < k) ? 1.0f : 0.0f;
            if (r == 2) out[b * 1024 + j] = gs;
        }
        float ks = block_reduce_sum_256(ls2, red4);
        if (tid == 0) {
            keff[r * Bb + b] = ks;
            out[131076 + r * Bb + b] = ks / fmaxf(teff, 1.0f);
        }
    }
}

// ---------------- 5a. pooling: per-chunk partials, no atomics -----------------
__global__ __launch_bounds__(256) void pool_kernel(
    const int* __restrict__ ids, const int* __restrict__ attn,
    const float* __restrict__ emb_table, const float* __restrict__ w_rho,
    float* __restrict__ ppart)   // [16 chunks][4 slots][32][768]
{
    const int b = blockIdx.x >> 4, chunk = blockIdx.x & 15;
    const int tid = threadIdx.x;
    float accF[3] = {0,0,0}, acc0[3] = {0,0,0}, acc1[3] = {0,0,0}, acc2[3] = {0,0,0};
    const int t0 = chunk * 64;
    for (int t = t0; t < t0 + 64; ++t) {
        int gi = b * 1024 + t;
        if (attn[gi] == 0) continue;
        float w0 = w_rho[gi], wa = w_rho[BT + gi], wb = w_rho[2 * BT + gi];
        const float* row = emb_table + (size_t)ids[gi] * 768;
        #pragma unroll
        for (int e = 0; e < 3; ++e) {
            float v = row[tid + 256 * e];
            accF[e] += v;
            acc0[e] = fmaf(w0, v, acc0[e]);
            acc1[e] = fmaf(wa, v, acc1[e]);
            acc2[e] = fmaf(wb, v, acc2[e]);
        }
    }
    float* base = ppart + ((size_t)chunk * 4 * Bb + b) * 768;
    #pragma unroll
    for (int e = 0; e < 3; ++e) {
        int d = tid + 256 * e;
        base[0 * Bb * 768 + d] = acc0[e];
        base[1 * Bb * 768 + d] = acc1[e];
        base[2 * Bb * 768 + d] = acc2[e];
        base[3 * Bb * 768 + d] = accF[e];
    }
}

// ---------------- 5b. reduce 16 chunk-partials -> pacc ------------------------
__global__ __launch_bounds__(256) void reduce_pacc_kernel(
    const float* __restrict__ ppart, float* __restrict__ pacc)
{
    int idx = blockIdx.x * 256 + threadIdx.x;   // 0 .. 4*32*768-1
    float s = 0.f;
    #pragma unroll
    for (int c = 0; c < 16; ++c) s += ppart[(size_t)c * 98304 + idx];
    pacc[idx] = s;
}

// ---------------- 6a. per-rho loss (3 blocks) ----------------
__global__ __launch_bounds__(256) void final3_kernel(
    const float* __restrict__ pacc, const float* __restrict__ keff,
    const float* __restrict__ stat, float* __restrict__ lsum, float* __restrict__ out)
{
    __shared__ float red4[4];
    const int r = blockIdx.x, tid = threadIdx.x;
    float local = 0.f;
    for (int idx = tid; idx < Bb * 768; idx += 256) {
        int b = idx / 768;
        int d = idx - b * 768;
        float fullv = pacc[(3 * Bb + b) * 768 + d] / fmaxf(stat[64 + b], 1e-9f);
        float predv = pacc[(r * Bb + b) * 768 + d] / fmaxf(keff[r * Bb + b], 1e-9f);
        float df = predv - fullv;
        local += df * df;
    }
    float tot = block_reduce_sum_256(local, red4);
    if (tid == 0) {
        float l = tot / 24576.0f;
        lsum[r] = l;
        out[131073 + r] = l;
    }
}

// ---------------- 6b. recon_avg ----------------
__global__ void final_avg_kernel(const float* __restrict__ lsum, float* __restrict__ out) {
    if (threadIdx.x == 0)
        out[131072] = (lsum[0] + lsum[1] + lsum[2]) / 3.0f;
}

// ---------------- launch ----------------
extern "C" void kernel_launch(void* const* d_in, const int* in_sizes, int n_in,
                              void* d_out, int out_size, void* d_ws, size_t ws_size,
                              hipStream_t stream) {
    const int*   ids       = (const int*)d_in[0];
    const float* emb       = (const float*)d_in[1];
    const int*   attn      = (const int*)d_in[2];
    const float* ln_g      = (const float*)d_in[3];
    const float* ln_b      = (const float*)d_in[4];
    const float* w1        = (const float*)d_in[5];
    const float* b1        = (const float*)d_in[6];
    const float* w2        = (const float*)d_in[7];
    const float* b2        = (const float*)d_in[8];
    const float* emb_table = (const float*)d_in[9];
    float* out = (float*)d_out;
    float* ws  = (float*)d_ws;

    float* scores = ws;                    // 32768
    float* ranks  = ws + 32768;            // 32768
    float* w_rho  = ws + 65536;            // 3*32768
    float* stat   = ws + 163840;           // 96
    float* keff   = ws + 163936;           // 96
    float* lsum   = ws + 164032;           // 16
    float* pacc   = ws + 164048;           // 98304 (ends 262352)
    int*   pos    = (int*)(ws + 262400);   // 32768
    int*   row_of = (int*)(ws + 295168);   // 32768
    int*   tok_of = (int*)(ws + 327936);   // 32768
    int*   segsum = (int*)(ws + 360704);   // 128
    int*   segbas = (int*)(ws + 360832);   // 128
    int*   mh     = (int*)(ws + 360960);   // 2
    short* a_hi   = (short*)(ws + 361216);         // 16384*768 shorts
    short* a_lo   = a_hi + (size_t)HALF_M * 768;   // 16384*768 shorts
    short* w1t_hi = a_lo + (size_t)HALF_M * 768;   // 1024*768 shorts
    short* w1t_lo = w1t_hi + 1024 * 768;           // 1024*768 shorts
    // pool partials alias a_hi's storage (dead after GEMM): 16*4*32*768 floats
    float* ppart  = (float*)a_hi;

    seg_count_kernel<<<128, 256, 0, stream>>>(attn, segsum);
    seg_scan_kernel<<<1, 128, 0, stream>>>(segsum, segbas, mh);
    cidx_kernel<<<128, 256, 0, stream>>>(attn, segbas, row_of, tok_of);
    init_scores_kernel<<<128, 256, 0, stream>>>(b2, attn, scores);
    prep_w1t_kernel<<<384, 256, 0, stream>>>(w1, w1t_hi, w1t_lo);

    for (int h = 0; h < 2; ++h) {
        prep_a_kernel<<<4096, 256, 0, stream>>>(
            emb + (size_t)h * HALF_M * 768, attn + h * HALF_M, row_of + h * HALF_M,
            ln_g, ln_b, a_hi, a_lo);
        score_gemm_mfma<<<1024, 512, 0, stream>>>(
            (const __bf16*)a_hi, (const __bf16*)a_lo,
            (const __bf16*)w1t_hi, (const __bf16*)w1t_lo,
            b1, w2, mh + h, tok_of + h * HALF_M, scores);
    }

    stats_kernel<<<32, 256, 0, stream>>>(scores, attn, stat);
    rank_kernel<<<512, 256, 0, stream>>>(scores, attn, stat, ranks, pos);
    gate_kernel<<<32, 256, 0, stream>>>(ranks, attn, stat, pos, w_rho, keff, out);
    pool_kernel<<<512, 256, 0, stream>>>(ids, attn, emb_table, w_rho, ppart);
    reduce_pacc_kernel<<<384, 256, 0, stream>>>(ppart, pacc);
    final3_kernel<<<3, 256, 0, stream>>>(pacc, keff, stat, lsum, out);
    final_avg_kernel<<<1, 64, 0, stream>>>(lsum, out);
}

// Round 7
// 317.708 us; speedup vs baseline: 2.9900x; 1.0193x over previous
//
#include <hip/hip_runtime.h>
#include <math.h>

#define BT 32768   // B*T
#define Dd 768
#define Hh 1024
#define Bb 32
#define Tt 1024
#define HALF_M 16384

typedef __bf16 bf16x8 __attribute__((ext_vector_type(8)));
typedef float f32x4 __attribute__((ext_vector_type(4)));

#define GL2LDS16(gp, lp) __builtin_amdgcn_global_load_lds( \
    (const __attribute__((address_space(1))) void*)(gp),   \
    (__attribute__((address_space(3))) void*)(lp), 16, 0, 0)

// ---------------- helpers ----------------
__device__ __forceinline__ float block_reduce_sum_256(float v, float* red4) {
    int tid = threadIdx.x;
    #pragma unroll
    for (int o = 32; o > 0; o >>= 1) v += __shfl_down(v, o);
    __syncthreads();
    if ((tid & 63) == 0) red4[tid >> 6] = v;
    __syncthreads();
    return red4[0] + red4[1] + red4[2] + red4[3];
}

__device__ __forceinline__ void bf16split(float x, short& h, short& l) {
    unsigned u = __float_as_uint(x);
    unsigned r = (u + 0x7FFFu + ((u >> 16) & 1u)) >> 16;     // RNE to bf16
    h = (short)r;
    float fh = __uint_as_float(r << 16);
    float lof = x - fh;
    unsigned u2 = __float_as_uint(lof);
    unsigned r2 = (u2 + 0x7FFFu + ((u2 >> 16) & 1u)) >> 16;
    l = (short)r2;
}

__device__ __forceinline__ int pack2(short a, short b) {
    return (int)(unsigned short)a | ((int)(unsigned short)b << 16);
}

// ---------------- 0a. per-256-token-segment active counts ----------------
__global__ __launch_bounds__(256) void seg_count_kernel(
    const int* __restrict__ attn, int* __restrict__ segsum)
{
    const int tid = threadIdx.x;
    int a = (attn[blockIdx.x * 256 + tid] != 0) ? 1 : 0;
    #pragma unroll
    for (int o = 32; o > 0; o >>= 1) a += __shfl_down(a, o);
    __shared__ int w4[4];
    if ((tid & 63) == 0) w4[tid >> 6] = a;
    __syncthreads();
    if (tid == 0) segsum[blockIdx.x] = w4[0] + w4[1] + w4[2] + w4[3];
}

// ---------------- 0b. parallel scan of 128 segments (wave = half) -------------
__global__ __launch_bounds__(128) void seg_scan_kernel(
    const int* __restrict__ segsum, int* __restrict__ seg_base, int* __restrict__ mh)
{
    const int tid = threadIdx.x;        // 0..127
    const int lane = tid & 63, w = tid >> 6;
    int v = segsum[tid];
    int s = v;
    #pragma unroll
    for (int o = 1; o < 64; o <<= 1) {
        int t = __shfl_up(s, o);
        if (lane >= o) s += t;
    }
    seg_base[tid] = s - v;              // exclusive within half
    if (lane == 63) mh[w] = s;          // active count per half
}

// ---------------- 0c. per-token compact row (ballot prefix) -------------------
__global__ __launch_bounds__(256) void cidx_kernel(
    const int* __restrict__ attn, const int* __restrict__ seg_base,
    int* __restrict__ row_of, int* __restrict__ tok_of)
{
    const int bid = blockIdx.x, tid = threadIdx.x;
    const int tok = bid * 256 + tid;
    const int active = (attn[tok] != 0) ? 1 : 0;
    unsigned long long m = __ballot(active);
    const int lane = tid & 63, wv = tid >> 6;
    __shared__ int wcnt[4];
    if (lane == 0) wcnt[wv] = __popcll(m);
    __syncthreads();
    int woff = 0;
    for (int q = 0; q < wv; ++q) woff += wcnt[q];
    int below = __popcll(m & ((1ULL << lane) - 1ULL));
    int row = seg_base[bid] + woff + below;          // row within half
    row_of[tok] = active ? row : -1;
    if (active) tok_of[(bid >> 6) * HALF_M + row] = tok;   // global token id
}

// ---------------- 1. prep A (per half): LN + bf16 hi/lo split, compacted ------
__global__ __launch_bounds__(256) void prep_a_kernel(
    const float* __restrict__ emb, const int* __restrict__ attn,
    const int* __restrict__ row_of,
    const float* __restrict__ ln_g, const float* __restrict__ ln_b,
    short* __restrict__ a_hi, short* __restrict__ a_lo)
{
    int tok  = blockIdx.x * 4 + (threadIdx.x >> 6);   // token within half
    int lane = threadIdx.x & 63;
    int av   = attn[tok];
    if (av == 0) return;                               // wave-uniform skip
    float af = (float)av;
    int row = row_of[tok];
    const float4* row4 = (const float4*)(emb + (size_t)tok * Dd);
    float4 x[3];
    #pragma unroll
    for (int e = 0; e < 3; ++e) x[e] = row4[lane + 64 * e];
    float s = 0.f;
    #pragma unroll
    for (int e = 0; e < 3; ++e) {
        x[e].x *= af; x[e].y *= af; x[e].z *= af; x[e].w *= af;
        s += x[e].x + x[e].y + x[e].z + x[e].w;
    }
    #pragma unroll
    for (int o = 32; o > 0; o >>= 1) s += __shfl_down(s, o);
    s = __shfl(s, 0);
    float mean = s / 768.0f;
    float q = 0.f;
    #pragma unroll
    for (int e = 0; e < 3; ++e) {
        float d0 = x[e].x - mean, d1 = x[e].y - mean, d2 = x[e].z - mean, d3 = x[e].w - mean;
        q += d0*d0 + d1*d1 + d2*d2 + d3*d3;
    }
    #pragma unroll
    for (int o = 32; o > 0; o >>= 1) q += __shfl_down(q, o);
    q = __shfl(q, 0);
    float rstd = 1.0f / sqrtf(q / 768.0f + 1e-5f);

    #pragma unroll
    for (int e = 0; e < 3; ++e) {
        int idx = lane * 4 + e * 256;
        float4 g4 = *(const float4*)(ln_g + idx);
        float4 b4 = *(const float4*)(ln_b + idx);
        float o0 = (x[e].x - mean) * rstd * g4.x + b4.x;
        float o1 = (x[e].y - mean) * rstd * g4.y + b4.y;
        float o2 = (x[e].z - mean) * rstd * g4.z + b4.z;
        float o3 = (x[e].w - mean) * rstd * g4.w + b4.w;
        short h0,h1,h2,h3,l0,l1,l2,l3;
        bf16split(o0,h0,l0); bf16split(o1,h1,l1);
        bf16split(o2,h2,l2); bf16split(o3,h3,l3);
        *(int2*)(a_hi + (size_t)row * 768 + idx) = make_int2(pack2(h0,h1), pack2(h2,h3));
        *(int2*)(a_lo + (size_t)row * 768 + idx) = make_int2(pack2(l0,l1), pack2(l2,l3));
    }
}

// ---------------- 2. prep W1^T: transpose + bf16 hi/lo split -------------------
__global__ __launch_bounds__(256) void prep_w1t_kernel(
    const float* __restrict__ w1, short* __restrict__ w1t_hi, short* __restrict__ w1t_lo)
{
    __shared__ float tile[32][65];
    const int kb  = blockIdx.x % 24;         // k block of 32
    const int nb0 = (blockIdx.x / 24) * 64;  // n block of 64
    const int tid = threadIdx.x;
    const int r0 = tid >> 6, c = tid & 63;
    #pragma unroll
    for (int rr = 0; rr < 8; ++rr) {
        int k = kb * 32 + r0 + rr * 4;
        tile[r0 + rr * 4][c] = w1[(size_t)k * 1024 + nb0 + c];
    }
    __syncthreads();
    const int n = tid >> 2, kc = (tid & 3) * 8;
    short h[8], lo[8];
    #pragma unroll
    for (int e = 0; e < 8; ++e) bf16split(tile[kc + e][n], h[e], lo[e]);
    size_t off = (size_t)(nb0 + n) * 768 + kb * 32 + kc;
    *(int4*)(w1t_hi + off) = make_int4(pack2(h[0],h[1]), pack2(h[2],h[3]),
                                       pack2(h[4],h[5]), pack2(h[6],h[7]));
    *(int4*)(w1t_lo + off) = make_int4(pack2(lo[0],lo[1]), pack2(lo[2],lo[3]),
                                       pack2(lo[4],lo[5]), pack2(lo[6],lo[7]));
}

// ---------------- 3a. init scores: b2 for active, 0 for padded ----------------
__global__ void init_scores_kernel(const float* __restrict__ b2,
                                   const int* __restrict__ attn,
                                   float* __restrict__ scores) {
    int i = blockIdx.x * 256 + threadIdx.x;
    scores[i] = (attn[i] != 0) ? b2[0] : 0.f;
}

// ---------------- 3b. MFMA GEMM, persistent blocks, XCD-partitioned A ---------
// grid = 512 persistent blocks. job = nc*MtPad + mt with MtPad % 8 == 0, so
// bid%8 == mt%8: all 8 nc-copies of an A-tile run on ONE XCD (single L2 fill),
// and every job (minus <=56 pad jobs) is live -> no idle CUs.
__global__ __launch_bounds__(512, 4) void score_gemm_mfma(
    const __bf16* __restrict__ a_hi, const __bf16* __restrict__ a_lo,
    const __bf16* __restrict__ w1t_hi, const __bf16* __restrict__ w1t_lo,
    const float* __restrict__ b1, const float* __restrict__ w2,
    const int* __restrict__ mh, const int* __restrict__ tok_of,
    float* __restrict__ scores)
{
    __shared__ __align__(16) __bf16 sAh[2][8][512];
    __shared__ __align__(16) __bf16 sAl[2][8][512];
    __shared__ __align__(16) __bf16 sBh[2][8][512];
    __shared__ __align__(16) __bf16 sBl[2][8][512];

    const int Mh    = mh[0];
    const int MtAct = (Mh + 127) >> 7;
    const int MtPad = (MtAct + 7) & ~7;
    const int njobs = MtPad * 8;

    const int tid = threadIdx.x;
    const int l   = tid & 63;
    const int w   = tid >> 6;            // 0..7
    const int rsel = l & 15;
    const int ksel = (l >> 4) * 8;
    const int wr   = w >> 2, wc = w & 3;  // 2 x 4 wave grid

    bool first = true;
    for (int job = blockIdx.x; job < njobs; job += 512) {
        const int mt = job % MtPad;
        const int m0 = mt * 128;
        if (m0 >= Mh) continue;                     // pad job (block-uniform)
        const int nc = job / MtPad;
        const int nb = nc * 128;

        if (!first) __syncthreads();                // drain previous job's LDS use
        first = false;

        const size_t aA = (size_t)(m0 + w * 16 + rsel) * 768 + ksel;
        const size_t aB = (size_t)(nb + w * 16 + rsel) * 768 + ksel;

        f32x4 acc[4][2];
        #pragma unroll
        for (int i = 0; i < 4; ++i)
            #pragma unroll
            for (int j = 0; j < 2; ++j) acc[i][j] = (f32x4){0.f, 0.f, 0.f, 0.f};

        auto stage = [&](int buf, int k0) {
            GL2LDS16(a_hi   + aA + k0, &sAh[buf][w][0]);
            GL2LDS16(a_lo   + aA + k0, &sAl[buf][w][0]);
            GL2LDS16(w1t_hi + aB + k0, &sBh[buf][w][0]);
            GL2LDS16(w1t_lo + aB + k0, &sBl[buf][w][0]);
        };

        stage(0, 0);

        for (int kt = 0; kt < 24; ++kt) {
            const int cur = kt & 1;
            __syncthreads();                   // stage(cur) landed; prior reads done
            if (kt < 23) stage(cur ^ 1, (kt + 1) * 32);

            bf16x8 ah[4], al[4], bh[2], bl[2];
            #pragma unroll
            for (int mi = 0; mi < 4; ++mi) {
                ah[mi] = *(const bf16x8*)&sAh[cur][wr * 4 + mi][l * 8];
                al[mi] = *(const bf16x8*)&sAl[cur][wr * 4 + mi][l * 8];
            }
            #pragma unroll
            for (int ni = 0; ni < 2; ++ni) {
                bh[ni] = *(const bf16x8*)&sBh[cur][wc * 2 + ni][l * 8];
                bl[ni] = *(const bf16x8*)&sBl[cur][wc * 2 + ni][l * 8];
            }
            #pragma unroll
            for (int mi = 0; mi < 4; ++mi)
                #pragma unroll
                for (int ni = 0; ni < 2; ++ni)
                    acc[mi][ni] = __builtin_amdgcn_mfma_f32_16x16x32_bf16(ah[mi], bh[ni], acc[mi][ni], 0, 0, 0);
            #pragma unroll
            for (int mi = 0; mi < 4; ++mi)
                #pragma unroll
                for (int ni = 0; ni < 2; ++ni)
                    acc[mi][ni] = __builtin_amdgcn_mfma_f32_16x16x32_bf16(al[mi], bh[ni], acc[mi][ni], 0, 0, 0);
            #pragma unroll
            for (int mi = 0; mi < 4; ++mi)
                #pragma unroll
                for (int ni = 0; ni < 2; ++ni)
                    acc[mi][ni] = __builtin_amdgcn_mfma_f32_16x16x32_bf16(ah[mi], bl[ni], acc[mi][ni], 0, 0, 0);
        }

        // epilogue: scores[tok_of[row]] += sum_col gelu(acc + b1[col]) * w2[col]
        const int colbase = nb + wc * 32 + (l & 15);
        const int rowg    = (l >> 4) * 4;
        #pragma unroll
        for (int mi = 0; mi < 4; ++mi) {
            float v[4] = {0.f, 0.f, 0.f, 0.f};
            #pragma unroll
            for (int ni = 0; ni < 2; ++ni) {
                int col = colbase + ni * 16;
                float b1v = b1[col], w2v = w2[col];
                #pragma unroll
                for (int j = 0; j < 4; ++j) {
                    float x = acc[mi][ni][j] + b1v;
                    float g = 0.5f * x * (1.0f + erff(x * 0.70710678118654752440f));
                    v[j] = fmaf(g, w2v, v[j]);
                }
            }
            #pragma unroll
            for (int j = 0; j < 4; ++j) {
                v[j] += __shfl_xor(v[j], 1);
                v[j] += __shfl_xor(v[j], 2);
                v[j] += __shfl_xor(v[j], 4);
                v[j] += __shfl_xor(v[j], 8);
            }
            if ((l & 15) == 0) {
                int rowb = m0 + wr * 64 + mi * 16 + rowg;
                #pragma unroll
                for (int j = 0; j < 4; ++j) {
                    int row = rowb + j;
                    if (row < Mh) atomicAdd(&scores[tok_of[row]], v[j]);
                }
            }
        }
    }
}

// ---------------- 4a. per-batch masked mean/var/T_eff of scores ----------------
__global__ __launch_bounds__(256) void stats_kernel(
    const float* __restrict__ scores, const int* __restrict__ attn,
    float* __restrict__ stat)  // [0..31]=mean [32..63]=rinv [64..95]=teff
{
    __shared__ float red4[4];
    const int b = blockIdx.x, tid = threadIdx.x;
    float sv[4], av[4];
    float sa = 0.f, ss = 0.f;
    #pragma unroll
    for (int e = 0; e < 4; ++e) {
        int i = tid + 256 * e;
        float af = (float)attn[b * 1024 + i];
        float s  = (af != 0.f) ? scores[b * 1024 + i] : 0.f;
        av[e] = af; sv[e] = s;
        sa += af; ss += s;
    }
    float tot_a = block_reduce_sum_256(sa, red4);
    float tot_s = block_reduce_sum_256(ss, red4);
    float denom = fmaxf(tot_a, 1.0f);
    float mean  = tot_s / denom;
    float q = 0.f;
    #pragma unroll
    for (int e = 0; e < 4; ++e) { float d = sv[e] - mean; q += d * d * av[e]; }
    float tot_q = block_reduce_sum_256(q, red4);
    if (tid == 0) {
        stat[b]      = mean;
        stat[32 + b] = 1.0f / sqrtf(tot_q / denom + 1e-6f);
        stat[64 + b] = tot_a;
    }
}

// ---------------- 4b. ranks + pos; 512 blocks (32 b x 16 chunks of 64 j) ------
__global__ __launch_bounds__(256) void rank_kernel(
    const float* __restrict__ scores, const int* __restrict__ attn,
    const float* __restrict__ stat, float* __restrict__ ranks,
    int* __restrict__ pos)
{
    __shared__ float sn[1024];
    __shared__ float afs[1024];
    __shared__ double dsum[256];
    __shared__ int    csum[256];
    const int b = blockIdx.x >> 4, qc = blockIdx.x & 15;
    const int tid = threadIdx.x;
    const float mean = stat[b], rinv = stat[32 + b];
    #pragma unroll
    for (int e = 0; e < 4; ++e) {
        int i = tid + 256 * e;
        float af = (float)attn[b * 1024 + i];
        float s  = (af != 0.f) ? scores[b * 1024 + i] : 0.f;
        sn[i]  = (s - mean) * rinv;
        afs[i] = af;
    }
    __syncthreads();
    const int jj = tid & 63;
    const int qt = tid >> 6;        // i-quarter 0..3
    const int j  = qc * 64 + jj;
    const float sj = sn[j];
    const bool  aj = (afs[j] != 0.f);
    double sum = 0.0;
    int    cnt = 0;
    const int i0 = qt * 256;
    #pragma unroll 4
    for (int i = i0; i < i0 + 256; ++i) {
        float si = sn[i];
        float ai = afs[i];
        float d   = (sj - si) * 20.0f;   // 1/tau
        float ee  = expf(-fabsf(d));
        float rcp = 1.0f / (1.0f + ee);
        float sig = (d >= 0.f) ? rcp : ee * rcp;
        sum += (double)(sig * sig);
        bool c;
        if (ai != 0.f) c = aj ? (si < sj || (si == sj && i < j)) : true;
        else           c = aj ? false : (i < j);
        cnt += c ? 1 : 0;
    }
    dsum[tid] = sum; csum[tid] = cnt;
    __syncthreads();
    if (tid < 64) {
        double s2 = dsum[tid] + dsum[tid + 64] + dsum[tid + 128] + dsum[tid + 192];
        int    c2 = csum[tid] + csum[tid + 64] + csum[tid + 128] + csum[tid + 192];
        int gj = b * 1024 + qc * 64 + tid;
        ranks[gj] = (afs[qc * 64 + tid] == 0.f) ? 1e9f : (float)(1.0 + s2);
        pos[gj]   = c2;
    }
}

// ---------------- 4c. gates + g_soft + hard_mask + rho_eff --------------------
__global__ __launch_bounds__(256) void gate_kernel(
    const float* __restrict__ ranks, const int* __restrict__ attn,
    const float* __restrict__ stat, const int* __restrict__ pos,
    float* __restrict__ w_rho, float* __restrict__ keff, float* __restrict__ out)
{
    __shared__ float red4[4];
    const int b = blockIdx.x, tid = threadIdx.x;
    const float teff = stat[64 + b];
    float rj[4], afj[4];
    int pj[4];
    #pragma unroll
    for (int e = 0; e < 4; ++e) {
        int j = tid + 256 * e;
        rj[e]  = ranks[b * 1024 + j];
        afj[e] = (float)attn[b * 1024 + j];
        pj[e]  = pos[b * 1024 + j];
    }
    const float rhos[3] = {0.1f, 0.25f, 0.5f};
    #pragma unroll 1
    for (int r = 0; r < 3; ++r) {
        float k = fmaxf(rintf(rhos[r] * teff), 1.0f);
        float gate[4]; float lsum = 0.f;
        #pragma unroll
        for (int e = 0; e < 4; ++e) {
            float d   = (k - rj[e]) / 0.2f;
            float ee  = expf(-fabsf(d));
            float rcp = 1.0f / (1.0f + ee);
            float sig = (d >= 0.f) ? rcp : ee * rcp;
            gate[e] = sig * afj[e];
            lsum += gate[e];
        }
        float gsum = block_reduce_sum_256(lsum, red4);
        float cl   = fmaxf(gsum, 1e-8f);
        float ls2  = 0.f;
        #pragma unroll
        for (int e = 0; e < 4; ++e) {
            int j = tid + 256 * e;
            float gs = gate[e] / cl * k;
            ls2 += gs;
            w_rho[r * BT + b * 1024 + j]     = gs;
            out[BT + r * BT + b * 1024 + j]  = ((float)pj[e] < k) ? 1.0f : 0.0f;
            if (r == 2) out[b * 1024 + j] = gs;
        }
        float ks = block_reduce_sum_256(ls2, red4);
        if (tid == 0) {
            keff[r * Bb + b] = ks;
            out[131076 + r * Bb + b] = ks / fmaxf(teff, 1.0f);
        }
    }
}

// ---------------- 5a. pooling: per-chunk partials, no atomics -----------------
__global__ __launch_bounds__(256) void pool_kernel(
    const int* __restrict__ ids, const int* __restrict__ attn,
    const float* __restrict__ emb_table, const float* __restrict__ w_rho,
    float* __restrict__ ppart)   // [16 chunks][4 slots][32][768]
{
    const int b = blockIdx.x >> 4, chunk = blockIdx.x & 15;
    const int tid = threadIdx.x;
    float accF[3] = {0,0,0}, acc0[3] = {0,0,0}, acc1[3] = {0,0,0}, acc2[3] = {0,0,0};
    const int t0 = chunk * 64;
    for (int t = t0; t < t0 + 64; ++t) {
        int gi = b * 1024 + t;
        if (attn[gi] == 0) continue;
        float w0 = w_rho[gi], wa = w_rho[BT + gi], wb = w_rho[2 * BT + gi];
        const float* row = emb_table + (size_t)ids[gi] * 768;
        #pragma unroll
        for (int e = 0; e < 3; ++e) {
            float v = row[tid + 256 * e];
            accF[e] += v;
            acc0[e] = fmaf(w0, v, acc0[e]);
            acc1[e] = fmaf(wa, v, acc1[e]);
            acc2[e] = fmaf(wb, v, acc2[e]);
        }
    }
    float* base = ppart + ((size_t)chunk * 4 * Bb + b) * 768;
    #pragma unroll
    for (int e = 0; e < 3; ++e) {
        int d = tid + 256 * e;
        base[0 * Bb * 768 + d] = acc0[e];
        base[1 * Bb * 768 + d] = acc1[e];
        base[2 * Bb * 768 + d] = acc2[e];
        base[3 * Bb * 768 + d] = accF[e];
    }
}

// ---------------- 5b. reduce 16 chunk-partials -> pacc ------------------------
__global__ __launch_bounds__(256) void reduce_pacc_kernel(
    const float* __restrict__ ppart, float* __restrict__ pacc)
{
    int idx = blockIdx.x * 256 + threadIdx.x;   // 0 .. 4*32*768-1
    float s = 0.f;
    #pragma unroll
    for (int c = 0; c < 16; ++c) s += ppart[(size_t)c * 98304 + idx];
    pacc[idx] = s;
}

// ---------------- 6a. per-rho loss (3 blocks) ----------------
__global__ __launch_bounds__(256) void final3_kernel(
    const float* __restrict__ pacc, const float* __restrict__ keff,
    const float* __restrict__ stat, float* __restrict__ lsum, float* __restrict__ out)
{
    __shared__ float red4[4];
    const int r = blockIdx.x, tid = threadIdx.x;
    float local = 0.f;
    for (int idx = tid; idx < Bb * 768; idx += 256) {
        int b = idx / 768;
        int d = idx - b * 768;
        float fullv = pacc[(3 * Bb + b) * 768 + d] / fmaxf(stat[64 + b], 1e-9f);
        float predv = pacc[(r * Bb + b) * 768 + d] / fmaxf(keff[r * Bb + b], 1e-9f);
        float df = predv - fullv;
        local += df * df;
    }
    float tot = block_reduce_sum_256(local, red4);
    if (tid == 0) {
        float l = tot / 24576.0f;
        lsum[r] = l;
        out[131073 + r] = l;
    }
}

// ---------------- 6b. recon_avg ----------------
__global__ void final_avg_kernel(const float* __restrict__ lsum, float* __restrict__ out) {
    if (threadIdx.x == 0)
        out[131072] = (lsum[0] + lsum[1] + lsum[2]) / 3.0f;
}

// ---------------- launch ----------------
extern "C" void kernel_launch(void* const* d_in, const int* in_sizes, int n_in,
                              void* d_out, int out_size, void* d_ws, size_t ws_size,
                              hipStream_t stream) {
    const int*   ids       = (const int*)d_in[0];
    const float* emb       = (const float*)d_in[1];
    const int*   attn      = (const int*)d_in[2];
    const float* ln_g      = (const float*)d_in[3];
    const float* ln_b      = (const float*)d_in[4];
    const float* w1        = (const float*)d_in[5];
    const float* b1        = (const float*)d_in[6];
    const float* w2        = (const float*)d_in[7];
    const float* b2        = (const float*)d_in[8];
    const float* emb_table = (const float*)d_in[9];
    float* out = (float*)d_out;
    float* ws  = (float*)d_ws;

    float* scores = ws;                    // 32768
    float* ranks  = ws + 32768;            // 32768
    float* w_rho  = ws + 65536;            // 3*32768
    float* stat   = ws + 163840;           // 96
    float* keff   = ws + 163936;           // 96
    float* lsum   = ws + 164032;           // 16
    float* pacc   = ws + 164048;           // 98304 (ends 262352)
    int*   pos    = (int*)(ws + 262400);   // 32768
    int*   row_of = (int*)(ws + 295168);   // 32768
    int*   tok_of = (int*)(ws + 327936);   // 32768
    int*   segsum = (int*)(ws + 360704);   // 128
    int*   segbas = (int*)(ws + 360832);   // 128
    int*   mh     = (int*)(ws + 360960);   // 2
    short* a_hi   = (short*)(ws + 361216);         // 16384*768 shorts
    short* a_lo   = a_hi + (size_t)HALF_M * 768;   // 16384*768 shorts
    short* w1t_hi = a_lo + (size_t)HALF_M * 768;   // 1024*768 shorts
    short* w1t_lo = w1t_hi + 1024 * 768;           // 1024*768 shorts
    // pool partials alias a_hi's storage (dead after GEMM): 16*4*32*768 floats
    float* ppart  = (float*)a_hi;

    seg_count_kernel<<<128, 256, 0, stream>>>(attn, segsum);
    seg_scan_kernel<<<1, 128, 0, stream>>>(segsum, segbas, mh);
    cidx_kernel<<<128, 256, 0, stream>>>(attn, segbas, row_of, tok_of);
    init_scores_kernel<<<128, 256, 0, stream>>>(b2, attn, scores);
    prep_w1t_kernel<<<384, 256, 0, stream>>>(w1, w1t_hi, w1t_lo);

    for (int h = 0; h < 2; ++h) {
        prep_a_kernel<<<4096, 256, 0, stream>>>(
            emb + (size_t)h * HALF_M * 768, attn + h * HALF_M, row_of + h * HALF_M,
            ln_g, ln_b, a_hi, a_lo);
        score_gemm_mfma<<<512, 512, 0, stream>>>(
            (const __bf16*)a_hi, (const __bf16*)a_lo,
            (const __bf16*)w1t_hi, (const __bf16*)w1t_lo,
            b1, w2, mh + h, tok_of + h * HALF_M, scores);
    }

    stats_kernel<<<32, 256, 0, stream>>>(scores, attn, stat);
    rank_kernel<<<512, 256, 0, stream>>>(scores, attn, stat, ranks, pos);
    gate_kernel<<<32, 256, 0, stream>>>(ranks, attn, stat, pos, w_rho, keff, out);
    pool_kernel<<<512, 256, 0, stream>>>(ids, attn, emb_table, w_rho, ppart);
    reduce_pacc_kernel<<<384, 256, 0, stream>>>(ppart, pacc);
    final3_kernel<<<3, 256, 0, stream>>>(pacc, keff, stat, lsum, out);
    final_avg_kernel<<<1, 64, 0, stream>>>(lsum, out);
}